// Round 5
// baseline (2395.518 us; speedup 1.0000x reference)
//
#include <hip/hip_runtime.h>
#include <hip/hip_bf16.h>
#include <math.h>

typedef __bf16 bf16_t;
typedef __bf16 bf16x4v __attribute__((ext_vector_type(4)));
typedef __bf16 bf16x8v __attribute__((ext_vector_type(8)));
typedef float  f32x4v  __attribute__((ext_vector_type(4)));

#define MFMA(a,b,c) __builtin_amdgcn_mfma_f32_16x16x32_bf16(a,b,c,0,0,0)

constexpr int B_ = 8, N_ = 1024, IN_ = 2048, DIM_ = 512, H_ = 8, DH_ = 64;
constexpr int DEPTH_ = 2, E_ = 4, C_ = 10, S_ = 1025;
constexpr int SP = 1152;        // padded seq len for q/k/v buffers (9*128)
constexpr int MP = 8320;        // padded row count for activations (65*128)
constexpr int MROWS = B_ * S_;  // 8200 valid rows per expert
constexpr size_t QKV_SLICE = (size_t)B_ * H_ * SP * DH_;  // one expert's q (or k/v)

// ---------------------------------------------------------------- async copy
__device__ __forceinline__ void async16(const void* g, void* l) {
  __builtin_amdgcn_global_load_lds((const __attribute__((address_space(1))) void*)g,
                                   (__attribute__((address_space(3))) void*)l, 16, 0, 0);
}

// ------------------------------------------------------- shared GEMM mainloop
// C[128x128] tile = A[128xK] * B^T[128xK]^T.  Both operands stored [rows][K]
// (weights pre-transposed), so A- and B-fragments are contiguous b128 reads.
// 4 waves in 2x2; each wave computes 64x64 via 4x4 grid of 16x16x32 MFMAs.
__device__ __forceinline__ void gemm_core(const bf16_t* __restrict__ A,
                                          const bf16_t* __restrict__ Bm, int K,
                                          bf16_t* As, bf16_t* Bs,
                                          f32x4v acc[4][4]) {
  const int tid  = threadIdx.x;
  const int lane = tid & 63, wave = tid >> 6;
  const int fr = lane & 15, fk = (lane >> 4) * 8;
  const int wm = (wave >> 1) * 64, wn = (wave & 1) * 64;
  // staging: wave w fills rows [w*32, w*32+32) of both tiles (2x 1KiB chunks each)
  const int srow = wave * 32 + (lane >> 2);
  const int scol = (lane & 3) * 8;
  const bf16_t* ga = A  + (size_t)srow * K + scol;
  const bf16_t* gb = Bm + (size_t)srow * K + scol;
  bf16_t* la = As + wave * 1024;  // wave-uniform LDS base; HW adds lane*16B
  bf16_t* lb = Bs + wave * 1024;
  for (int k0 = 0; k0 < K; k0 += 32) {
    async16(ga + k0,          la);
    async16(ga + k0 + 16 * K, la + 512);
    async16(gb + k0,          lb);
    async16(gb + k0 + 16 * K, lb + 512);
    __syncthreads();   // drains vmcnt(0): staged data visible
    bf16x8v af[4], bfr[4];
#pragma unroll
    for (int mt = 0; mt < 4; mt++)
      af[mt] = *(const bf16x8v*)&As[(wm + mt * 16 + fr) * 32 + fk];
#pragma unroll
    for (int nt = 0; nt < 4; nt++)
      bfr[nt] = *(const bf16x8v*)&Bs[(wn + nt * 16 + fr) * 32 + fk];
#pragma unroll
    for (int mt = 0; mt < 4; mt++)
#pragma unroll
      for (int nt = 0; nt < 4; nt++)
        acc[mt][nt] = MFMA(af[mt], bfr[nt], acc[mt][nt]);
    __syncthreads();   // all reads done before next stage overwrites
  }
}

// epilogue index helper: global row/col base for (mt,nt,r) iteration
#define EPI_SETUP()                                                    \
  int lane = threadIdx.x & 63, wave = threadIdx.x >> 6;                \
  int rb = blockIdx.x * 128 + (wave >> 1) * 64 + ((lane >> 4) << 2);   \
  int cb = blockIdx.y * 128 + (wave & 1) * 64 + (lane & 15);

// ----------------------------------------------------------------- converts
__global__ __launch_bounds__(256) void k_cvt(const float* __restrict__ in,
                                             bf16_t* __restrict__ out, int n4) {
  int i = blockIdx.x * blockDim.x + threadIdx.x;
  if (i < n4) {
    float4 v = ((const float4*)in)[i];
    bf16x4v o = {(bf16_t)v.x, (bf16_t)v.y, (bf16_t)v.z, (bf16_t)v.w};
    ((bf16x4v*)out)[i] = o;
  }
}

// in [nmat][K][N] f32 -> out [nmat][N][K] bf16 (K,N multiples of 32)
__global__ __launch_bounds__(256) void k_tcvt(const float* __restrict__ in,
                                              bf16_t* __restrict__ out, int K, int N) {
  __shared__ float tile[32][33];
  size_t mb = (size_t)blockIdx.z * K * N;
  int k0 = blockIdx.y * 32, n0 = blockIdx.x * 32;
  int tx = threadIdx.x, ty = threadIdx.y;
#pragma unroll
  for (int i = 0; i < 32; i += 8)
    tile[ty + i][tx] = in[mb + (size_t)(k0 + ty + i) * N + n0 + tx];
  __syncthreads();
#pragma unroll
  for (int i = 0; i < 32; i += 8)
    out[mb + (size_t)(n0 + ty + i) * K + k0 + tx] = (bf16_t)tile[tx][ty + i];
}

// ------------------------------------------------- proj GEMM (router+experts)
// z=0: router relu -> atomic mean-pool partials into racc[B][DIM]
// z=1..4: expert relu -> t[e][b][1+n][d]
__global__ __launch_bounds__(256) void k_gemm_proj(
    const bf16_t* __restrict__ xbf, const bf16_t* __restrict__ wrt,
    const bf16_t* __restrict__ wpt, const float* __restrict__ br,
    const float* __restrict__ bp, float* __restrict__ racc,
    float* __restrict__ t) {
  __shared__ bf16_t As[128 * 32], Bs[128 * 32];
  int z = blockIdx.z;
  const bf16_t* A  = xbf + (size_t)blockIdx.x * 128 * IN_;
  const bf16_t* Bm = (z == 0 ? wrt : wpt + (size_t)(z - 1) * DIM_ * IN_)
                     + (size_t)blockIdx.y * 128 * IN_;
  const float* bias = (z == 0) ? br : bp + (z - 1) * DIM_;
  f32x4v acc[4][4] = {};
  gemm_core(A, Bm, IN_, As, Bs, acc);
  EPI_SETUP();
  if (z == 0) {
    // all 128 rows of this block belong to batch b = blockIdx.x>>3
    int b = blockIdx.x >> 3;
    float part[4] = {0.f, 0.f, 0.f, 0.f};
#pragma unroll
    for (int mt = 0; mt < 4; mt++)
#pragma unroll
      for (int nt = 0; nt < 4; nt++)
#pragma unroll
        for (int r = 0; r < 4; r++)
          part[nt] += fmaxf(acc[mt][nt][r] + bias[cb + nt * 16], 0.f);
#pragma unroll
    for (int nt = 0; nt < 4; nt++)
      atomicAdd(&racc[b * DIM_ + cb + nt * 16], part[nt]);
  } else {
    int e = z - 1;
#pragma unroll
    for (int mt = 0; mt < 4; mt++)
#pragma unroll
      for (int nt = 0; nt < 4; nt++)
#pragma unroll
        for (int r = 0; r < 4; r++) {
          int row = rb + mt * 16 + r, col = cb + nt * 16;
          float v = fmaxf(acc[mt][nt][r] + bias[col], 0.f);
          int b = row >> 10, n = row & 1023;
          t[((size_t)(e * B_ + b) * S_ + 1 + n) * DIM_ + col] = v;
        }
  }
}

__global__ __launch_bounds__(512) void k_cls(const float* __restrict__ cls,
                                             float* __restrict__ t) {
  // block = (e*8+b); s=0 row
  t[(size_t)blockIdx.x * S_ * DIM_ + threadIdx.x] =
      cls[(blockIdx.x >> 3) * DIM_ + threadIdx.x];
}

// ------------------------------------------------------------------ router
__global__ __launch_bounds__(64) void k_router(const float* __restrict__ racc,
                                               const float* __restrict__ Wrf,
                                               const float* __restrict__ brf,
                                               float* __restrict__ gws,
                                               float* __restrict__ outg) {
  __shared__ float lg[8][4];
  int t = threadIdx.x;
  if (t < 32) {
    int b = t >> 2, e = t & 3;
    const float* r = racc + b * DIM_;
    float a = 0.f;
    for (int d = 0; d < DIM_; d++) a += r[d] * Wrf[d * 4 + e];
    lg[b][e] = a * (1.f / N_) + brf[e];
  }
  __syncthreads();
  if (t < 8) {
    int b = t;
    float mx = fmaxf(fmaxf(lg[b][0], lg[b][1]), fmaxf(lg[b][2], lg[b][3]));
    float s = 0.f, g[4];
#pragma unroll
    for (int e = 0; e < 4; e++) { g[e] = __expf(lg[b][e] - mx); s += g[e]; }
#pragma unroll
    for (int e = 0; e < 4; e++) {
      float gv = g[e] / s;
      gws[b * 4 + e] = gv;
      outg[b * 4 + e] = gv;
    }
  }
}

// --------------------------------------------------------------- layernorms
__global__ __launch_bounds__(256) void k_ln(const float* __restrict__ t,
                                            const float* __restrict__ gg,
                                            const float* __restrict__ bb, int l,
                                            bf16_t* __restrict__ h) {
  int s = blockIdx.x, b = blockIdx.y, e = blockIdx.z;
  const float* row = t + ((size_t)(e * B_ + b) * S_ + s) * DIM_;
  int tid = threadIdx.x;
  float v0 = row[tid], v1 = row[tid + 256];
  float sum = v0 + v1, sq = v0 * v0 + v1 * v1;
  for (int o = 32; o > 0; o >>= 1) {
    sum += __shfl_down(sum, o, 64);
    sq  += __shfl_down(sq, o, 64);
  }
  __shared__ float sb[8];
  int lane = tid & 63, wave = tid >> 6;
  if (lane == 0) { sb[wave * 2] = sum; sb[wave * 2 + 1] = sq; }
  __syncthreads();
  float ts = sb[0] + sb[2] + sb[4] + sb[6];
  float tq = sb[1] + sb[3] + sb[5] + sb[7];
  float mean = ts * (1.f / DIM_);
  float var  = tq * (1.f / DIM_) - mean * mean;
  float rstd = rsqrtf(var + 1e-5f);
  const float* gp = gg + (size_t)(e * DEPTH_ + l) * DIM_;
  const float* bp = bb + (size_t)(e * DEPTH_ + l) * DIM_;
  bf16_t* orow = h + ((size_t)e * MP + (size_t)b * S_ + s) * DIM_;
  orow[tid]       = (bf16_t)((v0 - mean) * rstd * gp[tid] + bp[tid]);
  orow[tid + 256] = (bf16_t)((v1 - mean) * rstd * gp[tid + 256] + bp[tid + 256]);
}

__global__ __launch_bounds__(256) void k_lnf(const float* __restrict__ t,
                                             const float* __restrict__ gg,
                                             const float* __restrict__ bb,
                                             float* __restrict__ lat) {
  int eb = blockIdx.x, e = eb >> 3;
  const float* row = t + (size_t)eb * S_ * DIM_;  // s=0 (cls)
  int tid = threadIdx.x;
  float v0 = row[tid], v1 = row[tid + 256];
  float sum = v0 + v1, sq = v0 * v0 + v1 * v1;
  for (int o = 32; o > 0; o >>= 1) {
    sum += __shfl_down(sum, o, 64);
    sq  += __shfl_down(sq, o, 64);
  }
  __shared__ float sb[8];
  int lane = tid & 63, wave = tid >> 6;
  if (lane == 0) { sb[wave * 2] = sum; sb[wave * 2 + 1] = sq; }
  __syncthreads();
  float ts = sb[0] + sb[2] + sb[4] + sb[6];
  float tq = sb[1] + sb[3] + sb[5] + sb[7];
  float mean = ts * (1.f / DIM_);
  float var  = tq * (1.f / DIM_) - mean * mean;
  float rstd = rsqrtf(var + 1e-5f);
  lat[(size_t)eb * DIM_ + tid]       = (v0 - mean) * rstd * gg[e * DIM_ + tid] + bb[e * DIM_ + tid];
  lat[(size_t)eb * DIM_ + tid + 256] = (v1 - mean) * rstd * gg[e * DIM_ + tid + 256] + bb[e * DIM_ + tid + 256];
}

// ------------------------------------- QKV GEMM (two experts: pair*2 + z)
__global__ __launch_bounds__(256) void k_gemm_qkv(
    const bf16_t* __restrict__ h, const bf16_t* __restrict__ wt,
    const float* __restrict__ bias, int pair, int l, bf16_t* __restrict__ qb,
    bf16_t* __restrict__ kb, bf16_t* __restrict__ vb) {
  __shared__ bf16_t As[128 * 32], Bs[128 * 32];
  int esub = blockIdx.z, e = pair * 2 + esub;
  size_t slice = (size_t)esub * QKV_SLICE;
  const bf16_t* A  = h + ((size_t)e * MP + blockIdx.x * 128) * DIM_;
  const bf16_t* Bm = wt + ((size_t)(e * DEPTH_ + l) * (3 * DIM_) + blockIdx.y * 128) * DIM_;
  const float* bp = bias + (size_t)(e * DEPTH_ + l) * (3 * DIM_);
  f32x4v acc[4][4] = {};
  gemm_core(A, Bm, DIM_, As, Bs, acc);
  EPI_SETUP();
#pragma unroll
  for (int mt = 0; mt < 4; mt++)
#pragma unroll
    for (int nt = 0; nt < 4; nt++)
#pragma unroll
      for (int r = 0; r < 4; r++) {
        int row = rb + mt * 16 + r;
        if (row < MROWS) {
          int col = cb + nt * 16;
          float v = acc[mt][nt][r] + bp[col];
          int b = row / S_, s = row - b * S_;
          int which = col >> 9, d = col & 511;
          int hh = d >> 6, dh = d & 63;
          size_t bh = (size_t)b * H_ + hh;
          bf16_t bv = (bf16_t)v;
          if (which == 0)      qb[slice + (bh * SP + s) * DH_ + dh] = bv;
          else if (which == 1) kb[slice + (bh * SP + s) * DH_ + dh] = bv;
          else                 vb[slice + bh * DH_ * SP + (size_t)dh * SP + s] = bv;  // V^T
        }
      }
}

// --------------------------------- flash attention (two experts per launch)
// block = (qt64, head, esub*8+b); 4 waves, each owns 16 q-rows (64-row
// q-tiles: 17x8x16 = 2176 blocks = 8.5/CU for TLP latency hiding; R4's
// 128-row tiles gave only 4.5/CU and 30% occupancy). K/V direct from global
// (L1/L2 absorb reuse -- R3 showed LDS staging is FETCH-neutral).
// No max-subtraction: scores are structurally tiny (LN-normed h x 0.02-scale
// Wqkv => |s| <~ 2), so p = exp2(s*c) cannot overflow fp32. Row-sum
// denominator via ones-matrix MFMA instead of cross-lane shuffles.
// P transits per-wave LDS (stride 72) for C-layout -> A-layout. No barriers.
__global__ __launch_bounds__(256, 8) void k_attn(const bf16_t* __restrict__ qb,
                                                 const bf16_t* __restrict__ kb,
                                                 const bf16_t* __restrict__ vb,
                                                 int pair, bf16_t* __restrict__ ob) {
  __shared__ bf16_t P[4][16 * 72];  // stride 72: even bank spread for b128 reads
  int qt = blockIdx.x, hh = blockIdx.y;
  int esub = blockIdx.z >> 3, b = blockIdx.z & 7;
  int e = pair * 2 + esub;
  size_t slice = (size_t)esub * QKV_SLICE;
  size_t bh = (size_t)b * H_ + hh;
  const bf16_t* Q = qb + slice + bh * SP * DH_;
  const bf16_t* K = kb + slice + bh * SP * DH_;
  const bf16_t* V = vb + slice + bh * DH_ * SP;
  int lane = threadIdx.x & 63, wave = threadIdx.x >> 6;
  int fr = lane & 15, q4 = lane >> 4;
  bf16_t* Pw = &P[wave][0];

  bf16x8v qf[2];
#pragma unroll
  for (int kk = 0; kk < 2; kk++)
    qf[kk] = *(const bf16x8v*)&Q[(size_t)(qt * 64 + wave * 16 + fr) * DH_
                                 + q4 * 8 + kk * 32];

  bf16x8v ones;
#pragma unroll
  for (int j = 0; j < 8; j++) ones[j] = (bf16_t)1.0f;

  f32x4v O[4] = {};
  f32x4v lacc = {};

  const float cl2e = 0.125f * 1.4426950408889634f;  // DH^-0.5 * log2(e)

  for (int kt = 0; kt < 17; kt++) {
    int ks = kt * 64;
    f32x4v sc[4] = {};
#pragma unroll
    for (int nt = 0; nt < 4; nt++) {
      bf16x8v kf0 = *(const bf16x8v*)&K[(size_t)(ks + nt * 16 + fr) * DH_ + q4 * 8];
      bf16x8v kf1 = *(const bf16x8v*)&K[(size_t)(ks + nt * 16 + fr) * DH_ + q4 * 8 + 32];
      sc[nt] = MFMA(qf[0], kf0, sc[nt]);
      sc[nt] = MFMA(qf[1], kf1, sc[nt]);
    }
    // mask invalid key columns (only last tile; forces p=0 there)
    if (ks + 64 > S_) {
#pragma unroll
      for (int nt = 0; nt < 4; nt++)
        if (ks + nt * 16 + fr >= S_) {
#pragma unroll
          for (int c = 0; c < 4; c++) sc[nt][c] = -1e30f;
        }
    }
    // p = exp2(s * c); write straight to per-wave LDS in C layout
#pragma unroll
    for (int nt = 0; nt < 4; nt++)
#pragma unroll
      for (int c = 0; c < 4; c++) {
        float p = exp2f(sc[nt][c] * cl2e);
        Pw[(q4 * 4 + c) * 72 + nt * 16 + fr] = (bf16_t)p;
      }
    // P @ V and P @ ones (rowsum) -- same-wave LDS write->read is in-order
#pragma unroll
    for (int kk = 0; kk < 2; kk++) {
      bf16x8v pa = *(const bf16x8v*)&Pw[fr * 72 + q4 * 8 + kk * 32];
      lacc = MFMA(pa, ones, lacc);
#pragma unroll
      for (int nt = 0; nt < 4; nt++) {
        bf16x8v vf = *(const bf16x8v*)&V[(size_t)(nt * 16 + fr) * SP + ks + q4 * 8 + kk * 32];
        O[nt] = MFMA(pa, vf, O[nt]);
      }
    }
  }
#pragma unroll
  for (int c = 0; c < 4; c++) {
    int s = qt * 64 + wave * 16 + q4 * 4 + c;
    if (s < S_) {
      float inv = 1.f / lacc[c];
#pragma unroll
      for (int nt = 0; nt < 4; nt++)
        ob[((size_t)e * MP + (size_t)b * S_ + s) * DIM_ + hh * DH_ + nt * 16 + fr]
            = (bf16_t)(O[nt][c] * inv);
    }
  }
}

// ------------------------------------------- GEMM + residual-add (Wo and W2)
__global__ __launch_bounds__(256) void k_gemm_res(
    const bf16_t* __restrict__ abuf, const bf16_t* __restrict__ wt,
    const float* __restrict__ bias, int l, float* __restrict__ t) {
  __shared__ bf16_t As[128 * 32], Bs[128 * 32];
  int e = blockIdx.z;
  const bf16_t* A  = abuf + ((size_t)e * MP + blockIdx.x * 128) * DIM_;
  const bf16_t* Bm = wt + ((size_t)(e * DEPTH_ + l) * DIM_ + blockIdx.y * 128) * DIM_;
  const float* bp = bias + (size_t)(e * DEPTH_ + l) * DIM_;
  f32x4v acc[4][4] = {};
  gemm_core(A, Bm, DIM_, As, Bs, acc);
  EPI_SETUP();
#pragma unroll
  for (int mt = 0; mt < 4; mt++)
#pragma unroll
    for (int nt = 0; nt < 4; nt++)
#pragma unroll
      for (int r = 0; r < 4; r++) {
        int row = rb + mt * 16 + r;
        if (row < MROWS) {
          int col = cb + nt * 16;
          t[((size_t)e * MROWS + row) * DIM_ + col] += acc[mt][nt][r] + bp[col];
        }
      }
}

// ----------------------------------------------------------- W1 GEMM + gelu
__global__ __launch_bounds__(256) void k_gemm_gelu(
    const bf16_t* __restrict__ abuf, const bf16_t* __restrict__ wt,
    const float* __restrict__ bias, int l, bf16_t* __restrict__ ub) {
  __shared__ bf16_t As[128 * 32], Bs[128 * 32];
  int e = blockIdx.z;
  const bf16_t* A  = abuf + ((size_t)e * MP + blockIdx.x * 128) * DIM_;
  const bf16_t* Bm = wt + ((size_t)(e * DEPTH_ + l) * DIM_ + blockIdx.y * 128) * DIM_;
  const float* bp = bias + (size_t)(e * DEPTH_ + l) * DIM_;
  f32x4v acc[4][4] = {};
  gemm_core(A, Bm, DIM_, As, Bs, acc);
  EPI_SETUP();
#pragma unroll
  for (int mt = 0; mt < 4; mt++)
#pragma unroll
    for (int nt = 0; nt < 4; nt++)
#pragma unroll
      for (int r = 0; r < 4; r++) {
        int row = rb + mt * 16 + r;
        if (row < MROWS) {
          int col = cb + nt * 16;
          float v = acc[mt][nt][r] + bp[col];
          // jax.nn.gelu default (approximate=True, tanh form)
          float u = 0.7978845608028654f * (v + 0.044715f * v * v * v);
          float g = 0.5f * v * (1.f + tanhf(u));
          ub[((size_t)e * MP + row) * DIM_ + col] = (bf16_t)g;
        }
      }
}

// ---------------------------------------------------------- head + mixtures
__global__ __launch_bounds__(256) void k_head(const float* __restrict__ lat,
                                              const float* __restrict__ Wh,
                                              const float* __restrict__ bh,
                                              const float* __restrict__ gws,
                                              float* __restrict__ out) {
  int b = blockIdx.x, tid = threadIdx.x;
  for (int d = tid; d < DIM_; d += 256) {
    float a = 0.f;
#pragma unroll
    for (int e = 0; e < 4; e++)
      a += gws[b * 4 + e] * lat[(size_t)(e * B_ + b) * DIM_ + d];
    out[b * DIM_ + d] = a;
  }
  __shared__ float lg[4][10];
  if (tid < 40) {
    int e = tid / 10, c = tid % 10;
    const float* le = lat + (size_t)(e * B_ + b) * DIM_;
    const float* w  = Wh + (size_t)e * DIM_ * C_;
    float a = 0.f;
    for (int d = 0; d < DIM_; d++) a += le[d] * w[d * C_ + c];
    lg[e][c] = a + bh[e * C_ + c];
  }
  __syncthreads();
  if (tid < 10) {
    float a = 0.f;
#pragma unroll
    for (int e = 0; e < 4; e++) a += gws[b * 4 + e] * lg[e][tid];
    out[B_ * DIM_ + b * C_ + tid] = a;
  }
}

// ------------------------------------------------------------------- launch
extern "C" void kernel_launch(void* const* d_in, const int* in_sizes, int n_in,
                              void* d_out, int out_size, void* d_ws, size_t ws_size,
                              hipStream_t stream) {
  const float* x    = (const float*)d_in[0];
  const float* Wr   = (const float*)d_in[1];
  const float* br   = (const float*)d_in[2];
  const float* Wrf  = (const float*)d_in[3];
  const float* brf  = (const float*)d_in[4];
  const float* Wp   = (const float*)d_in[5];
  const float* bp   = (const float*)d_in[6];
  const float* cls  = (const float*)d_in[7];
  const float* ln1g = (const float*)d_in[8];
  const float* ln1b = (const float*)d_in[9];
  const float* Wqkv = (const float*)d_in[10];
  const float* bqkv = (const float*)d_in[11];
  const float* Wo   = (const float*)d_in[12];
  const float* bo   = (const float*)d_in[13];
  const float* ln2g = (const float*)d_in[14];
  const float* ln2b = (const float*)d_in[15];
  const float* W1   = (const float*)d_in[16];
  const float* b1   = (const float*)d_in[17];
  const float* W2   = (const float*)d_in[18];
  const float* b2   = (const float*)d_in[19];
  const float* lnfg = (const float*)d_in[20];
  const float* lnfb = (const float*)d_in[21];
  const float* Wh   = (const float*)d_in[22];
  const float* bh   = (const float*)d_in[23];
  float* out = (float*)d_out;

  // ---- workspace layout (~210 MiB total; stream-ordered aliasing) ----
  char* w = (char*)d_ws;
  size_t off = 0;
  auto take = [&](size_t bytes) {
    void* p = w + off;
    off += (bytes + 255) & ~(size_t)255;
    return p;
  };
  // persistent region (~153 MiB)
  bf16_t* wqkv_t = (bf16_t*)take((size_t)E_ * DEPTH_ * 3 * DIM_ * DIM_ * 2);
  bf16_t* wo_t   = (bf16_t*)take((size_t)E_ * DEPTH_ * DIM_ * DIM_ * 2);
  bf16_t* w1_t   = (bf16_t*)take((size_t)E_ * DEPTH_ * DIM_ * DIM_ * 2);
  bf16_t* w2_t   = (bf16_t*)take((size_t)E_ * DEPTH_ * DIM_ * DIM_ * 2);
  float*  tbuf   = (float*)take((size_t)E_ * MROWS * DIM_ * 4);
  bf16_t* hbuf   = (bf16_t*)take((size_t)E_ * MP * DIM_ * 2);
  bf16_t* obuf   = (bf16_t*)take((size_t)E_ * MP * DIM_ * 2);  // attn out / W1 out
  float*  racc   = (float*)take((size_t)B_ * DIM_ * 4);
  float*  gws    = (float*)take((size_t)B_ * E_ * 4);
  float*  late   = (float*)take((size_t)E_ * B_ * DIM_ * 4);
  // union region (max of pre-loop view A=44 MiB, loop view B=57 MiB)
  char* uni = (char*)w + off;
  //   view A (dead after k_gemm_proj):
  bf16_t* x_bf = (bf16_t*)(uni);
  bf16_t* wr_t = (bf16_t*)(uni + (size_t)8192 * IN_ * 2);
  bf16_t* wp_t = (bf16_t*)(uni + (size_t)8192 * IN_ * 2 + (size_t)DIM_ * IN_ * 2);
  //   view B (2-expert q/k/v, rewritten every (l,pair)):
  size_t qkv2 = 2 * QKV_SLICE * 2;  // two experts, bytes
  bf16_t* qbuf = (bf16_t*)(uni);
  bf16_t* kbuf = (bf16_t*)(uni + qkv2);
  bf16_t* vbuf = (bf16_t*)(uni + 2 * qkv2);
  (void)in_sizes; (void)n_in; (void)out_size; (void)ws_size;

  // input + weight conversion (weights transposed to [N][K] bf16)
  int n4 = 8192 * IN_ / 4;
  k_cvt<<<(n4 + 255) / 256, 256, 0, stream>>>(x, x_bf, n4);
  dim3 tb(32, 8);
  k_tcvt<<<dim3(DIM_ / 32, IN_ / 32, 1), tb, 0, stream>>>(Wr, wr_t, IN_, DIM_);
  k_tcvt<<<dim3(DIM_ / 32, IN_ / 32, E_), tb, 0, stream>>>(Wp, wp_t, IN_, DIM_);
  k_tcvt<<<dim3(3 * DIM_ / 32, DIM_ / 32, E_ * DEPTH_), tb, 0, stream>>>(Wqkv, wqkv_t, DIM_, 3 * DIM_);
  k_tcvt<<<dim3(DIM_ / 32, DIM_ / 32, E_ * DEPTH_), tb, 0, stream>>>(Wo, wo_t, DIM_, DIM_);
  k_tcvt<<<dim3(DIM_ / 32, DIM_ / 32, E_ * DEPTH_), tb, 0, stream>>>(W1, w1_t, DIM_, DIM_);
  k_tcvt<<<dim3(DIM_ / 32, DIM_ / 32, E_ * DEPTH_), tb, 0, stream>>>(W2, w2_t, DIM_, DIM_);

  // router + expert input projections (z=0 router-pool, z=1..4 experts)
  hipMemsetAsync(racc, 0, (size_t)B_ * DIM_ * 4, stream);
  k_gemm_proj<<<dim3(64, 4, 5), 256, 0, stream>>>(x_bf, wr_t, wp_t, br, bp, racc, tbuf);
  k_cls<<<32, 512, 0, stream>>>(cls, tbuf);
  k_router<<<1, 64, 0, stream>>>(racc, Wrf, brf, gws, out + B_ * DIM_ + B_ * C_);

  for (int l = 0; l < DEPTH_; l++) {
    k_ln<<<dim3(S_, B_, E_), 256, 0, stream>>>(tbuf, ln1g, ln1b, l, hbuf);
    for (int pair = 0; pair < 2; pair++) {
      k_gemm_qkv<<<dim3(65, 12, 2), 256, 0, stream>>>(hbuf, wqkv_t, bqkv, pair, l, qbuf, kbuf, vbuf);
      k_attn<<<dim3(17, H_, 16), 256, 0, stream>>>(qbuf, kbuf, vbuf, pair, obuf);
    }
    k_gemm_res<<<dim3(65, 4, E_), 256, 0, stream>>>(obuf, wo_t, bo, l, tbuf);
    k_ln<<<dim3(S_, B_, E_), 256, 0, stream>>>(tbuf, ln2g, ln2b, l, hbuf);
    k_gemm_gelu<<<dim3(65, 4, E_), 256, 0, stream>>>(hbuf, w1_t, b1, l, obuf);
    k_gemm_res<<<dim3(65, 4, E_), 256, 0, stream>>>(obuf, w2_t, b2, l, tbuf);
  }
  k_lnf<<<32, 256, 0, stream>>>(tbuf, lnfg, lnfb, late);
  k_head<<<8, 256, 0, stream>>>(late, Wh, bh, gws, out);
}

// Round 6
// 1561.586 us; speedup vs baseline: 1.5340x; 1.5340x over previous
//
#include <hip/hip_runtime.h>
#include <hip/hip_bf16.h>
#include <math.h>

typedef __bf16 bf16_t;
typedef __bf16 bf16x4v __attribute__((ext_vector_type(4)));
typedef __bf16 bf16x8v __attribute__((ext_vector_type(8)));
typedef float  f32x4v  __attribute__((ext_vector_type(4)));

#define MFMA(a,b,c) __builtin_amdgcn_mfma_f32_16x16x32_bf16(a,b,c,0,0,0)

constexpr int B_ = 8, N_ = 1024, IN_ = 2048, DIM_ = 512, H_ = 8, DH_ = 64;
constexpr int DEPTH_ = 2, E_ = 4, C_ = 10, S_ = 1025;
constexpr int SP = 1152;        // padded seq len for q/k/v buffers (9*128)
constexpr int MP = 8320;        // padded row count for activations (65*128)
constexpr int MROWS = B_ * S_;  // 8200 valid rows per expert
constexpr size_t QKV_SLICE = (size_t)B_ * H_ * SP * DH_;  // one expert's q (or k/v)

// ---------------------------------------------------------------- async copy
__device__ __forceinline__ void async16(const void* g, void* l) {
  __builtin_amdgcn_global_load_lds((const __attribute__((address_space(1))) void*)g,
                                   (__attribute__((address_space(3))) void*)l, 16, 0, 0);
}

// ------------------------------------------------------- shared GEMM mainloop
// C[128x128] tile = A[128xK] * B^T[128xK]^T.  Both operands stored [rows][K]
// (weights pre-transposed), so A- and B-fragments are contiguous b128 reads.
// 4 waves in 2x2; each wave computes 64x64 via 4x4 grid of 16x16x32 MFMAs.
__device__ __forceinline__ void gemm_core(const bf16_t* __restrict__ A,
                                          const bf16_t* __restrict__ Bm, int K,
                                          bf16_t* As, bf16_t* Bs,
                                          f32x4v acc[4][4]) {
  const int tid  = threadIdx.x;
  const int lane = tid & 63, wave = tid >> 6;
  const int fr = lane & 15, fk = (lane >> 4) * 8;
  const int wm = (wave >> 1) * 64, wn = (wave & 1) * 64;
  // staging: wave w fills rows [w*32, w*32+32) of both tiles (2x 1KiB chunks each)
  const int srow = wave * 32 + (lane >> 2);
  const int scol = (lane & 3) * 8;
  const bf16_t* ga = A  + (size_t)srow * K + scol;
  const bf16_t* gb = Bm + (size_t)srow * K + scol;
  bf16_t* la = As + wave * 1024;  // wave-uniform LDS base; HW adds lane*16B
  bf16_t* lb = Bs + wave * 1024;
  for (int k0 = 0; k0 < K; k0 += 32) {
    async16(ga + k0,          la);
    async16(ga + k0 + 16 * K, la + 512);
    async16(gb + k0,          lb);
    async16(gb + k0 + 16 * K, lb + 512);
    __syncthreads();   // drains vmcnt(0): staged data visible
    bf16x8v af[4], bfr[4];
#pragma unroll
    for (int mt = 0; mt < 4; mt++)
      af[mt] = *(const bf16x8v*)&As[(wm + mt * 16 + fr) * 32 + fk];
#pragma unroll
    for (int nt = 0; nt < 4; nt++)
      bfr[nt] = *(const bf16x8v*)&Bs[(wn + nt * 16 + fr) * 32 + fk];
#pragma unroll
    for (int mt = 0; mt < 4; mt++)
#pragma unroll
      for (int nt = 0; nt < 4; nt++)
        acc[mt][nt] = MFMA(af[mt], bfr[nt], acc[mt][nt]);
    __syncthreads();   // all reads done before next stage overwrites
  }
}

// epilogue index helper: global row/col base for (mt,nt,r) iteration
#define EPI_SETUP()                                                    \
  int lane = threadIdx.x & 63, wave = threadIdx.x >> 6;                \
  int rb = blockIdx.x * 128 + (wave >> 1) * 64 + ((lane >> 4) << 2);   \
  int cb = blockIdx.y * 128 + (wave & 1) * 64 + (lane & 15);

// ----------------------------------------------------------------- converts
__global__ __launch_bounds__(256) void k_cvt(const float* __restrict__ in,
                                             bf16_t* __restrict__ out, int n4) {
  int i = blockIdx.x * blockDim.x + threadIdx.x;
  if (i < n4) {
    float4 v = ((const float4*)in)[i];
    bf16x4v o = {(bf16_t)v.x, (bf16_t)v.y, (bf16_t)v.z, (bf16_t)v.w};
    ((bf16x4v*)out)[i] = o;
  }
}

// in [nmat][K][N] f32 -> out [nmat][N][K] bf16 (K,N multiples of 32)
__global__ __launch_bounds__(256) void k_tcvt(const float* __restrict__ in,
                                              bf16_t* __restrict__ out, int K, int N) {
  __shared__ float tile[32][33];
  size_t mb = (size_t)blockIdx.z * K * N;
  int k0 = blockIdx.y * 32, n0 = blockIdx.x * 32;
  int tx = threadIdx.x, ty = threadIdx.y;
#pragma unroll
  for (int i = 0; i < 32; i += 8)
    tile[ty + i][tx] = in[mb + (size_t)(k0 + ty + i) * N + n0 + tx];
  __syncthreads();
#pragma unroll
  for (int i = 0; i < 32; i += 8)
    out[mb + (size_t)(n0 + ty + i) * K + k0 + tx] = (bf16_t)tile[tx][ty + i];
}

// ------------------------------------------------- proj GEMM (router+experts)
// z=0: router relu -> atomic mean-pool partials into racc[B][DIM]
// z=1..4: expert relu -> t[e][b][1+n][d]
__global__ __launch_bounds__(256) void k_gemm_proj(
    const bf16_t* __restrict__ xbf, const bf16_t* __restrict__ wrt,
    const bf16_t* __restrict__ wpt, const float* __restrict__ br,
    const float* __restrict__ bp, float* __restrict__ racc,
    float* __restrict__ t) {
  __shared__ bf16_t As[128 * 32], Bs[128 * 32];
  int z = blockIdx.z;
  const bf16_t* A  = xbf + (size_t)blockIdx.x * 128 * IN_;
  const bf16_t* Bm = (z == 0 ? wrt : wpt + (size_t)(z - 1) * DIM_ * IN_)
                     + (size_t)blockIdx.y * 128 * IN_;
  const float* bias = (z == 0) ? br : bp + (z - 1) * DIM_;
  f32x4v acc[4][4] = {};
  gemm_core(A, Bm, IN_, As, Bs, acc);
  EPI_SETUP();
  if (z == 0) {
    // all 128 rows of this block belong to batch b = blockIdx.x>>3
    int b = blockIdx.x >> 3;
    float part[4] = {0.f, 0.f, 0.f, 0.f};
#pragma unroll
    for (int mt = 0; mt < 4; mt++)
#pragma unroll
      for (int nt = 0; nt < 4; nt++)
#pragma unroll
        for (int r = 0; r < 4; r++)
          part[nt] += fmaxf(acc[mt][nt][r] + bias[cb + nt * 16], 0.f);
#pragma unroll
    for (int nt = 0; nt < 4; nt++)
      atomicAdd(&racc[b * DIM_ + cb + nt * 16], part[nt]);
  } else {
    int e = z - 1;
#pragma unroll
    for (int mt = 0; mt < 4; mt++)
#pragma unroll
      for (int nt = 0; nt < 4; nt++)
#pragma unroll
        for (int r = 0; r < 4; r++) {
          int row = rb + mt * 16 + r, col = cb + nt * 16;
          float v = fmaxf(acc[mt][nt][r] + bias[col], 0.f);
          int b = row >> 10, n = row & 1023;
          t[((size_t)(e * B_ + b) * S_ + 1 + n) * DIM_ + col] = v;
        }
  }
}

__global__ __launch_bounds__(512) void k_cls(const float* __restrict__ cls,
                                             float* __restrict__ t) {
  // block = (e*8+b); s=0 row
  t[(size_t)blockIdx.x * S_ * DIM_ + threadIdx.x] =
      cls[(blockIdx.x >> 3) * DIM_ + threadIdx.x];
}

// ------------------------------------------------------------------ router
__global__ __launch_bounds__(64) void k_router(const float* __restrict__ racc,
                                               const float* __restrict__ Wrf,
                                               const float* __restrict__ brf,
                                               float* __restrict__ gws,
                                               float* __restrict__ outg) {
  __shared__ float lg[8][4];
  int t = threadIdx.x;
  if (t < 32) {
    int b = t >> 2, e = t & 3;
    const float* r = racc + b * DIM_;
    float a = 0.f;
    for (int d = 0; d < DIM_; d++) a += r[d] * Wrf[d * 4 + e];
    lg[b][e] = a * (1.f / N_) + brf[e];
  }
  __syncthreads();
  if (t < 8) {
    int b = t;
    float mx = fmaxf(fmaxf(lg[b][0], lg[b][1]), fmaxf(lg[b][2], lg[b][3]));
    float s = 0.f, g[4];
#pragma unroll
    for (int e = 0; e < 4; e++) { g[e] = __expf(lg[b][e] - mx); s += g[e]; }
#pragma unroll
    for (int e = 0; e < 4; e++) {
      float gv = g[e] / s;
      gws[b * 4 + e] = gv;
      outg[b * 4 + e] = gv;
    }
  }
}

// --------------------------------------------------------------- layernorms
__global__ __launch_bounds__(256) void k_ln(const float* __restrict__ t,
                                            const float* __restrict__ gg,
                                            const float* __restrict__ bb, int l,
                                            bf16_t* __restrict__ h) {
  int s = blockIdx.x, b = blockIdx.y, e = blockIdx.z;
  const float* row = t + ((size_t)(e * B_ + b) * S_ + s) * DIM_;
  int tid = threadIdx.x;
  float v0 = row[tid], v1 = row[tid + 256];
  float sum = v0 + v1, sq = v0 * v0 + v1 * v1;
  for (int o = 32; o > 0; o >>= 1) {
    sum += __shfl_down(sum, o, 64);
    sq  += __shfl_down(sq, o, 64);
  }
  __shared__ float sb[8];
  int lane = tid & 63, wave = tid >> 6;
  if (lane == 0) { sb[wave * 2] = sum; sb[wave * 2 + 1] = sq; }
  __syncthreads();
  float ts = sb[0] + sb[2] + sb[4] + sb[6];
  float tq = sb[1] + sb[3] + sb[5] + sb[7];
  float mean = ts * (1.f / DIM_);
  float var  = tq * (1.f / DIM_) - mean * mean;
  float rstd = rsqrtf(var + 1e-5f);
  const float* gp = gg + (size_t)(e * DEPTH_ + l) * DIM_;
  const float* bp = bb + (size_t)(e * DEPTH_ + l) * DIM_;
  bf16_t* orow = h + ((size_t)e * MP + (size_t)b * S_ + s) * DIM_;
  orow[tid]       = (bf16_t)((v0 - mean) * rstd * gp[tid] + bp[tid]);
  orow[tid + 256] = (bf16_t)((v1 - mean) * rstd * gp[tid + 256] + bp[tid + 256]);
}

__global__ __launch_bounds__(256) void k_lnf(const float* __restrict__ t,
                                             const float* __restrict__ gg,
                                             const float* __restrict__ bb,
                                             float* __restrict__ lat) {
  int eb = blockIdx.x, e = eb >> 3;
  const float* row = t + (size_t)eb * S_ * DIM_;  // s=0 (cls)
  int tid = threadIdx.x;
  float v0 = row[tid], v1 = row[tid + 256];
  float sum = v0 + v1, sq = v0 * v0 + v1 * v1;
  for (int o = 32; o > 0; o >>= 1) {
    sum += __shfl_down(sum, o, 64);
    sq  += __shfl_down(sq, o, 64);
  }
  __shared__ float sb[8];
  int lane = tid & 63, wave = tid >> 6;
  if (lane == 0) { sb[wave * 2] = sum; sb[wave * 2 + 1] = sq; }
  __syncthreads();
  float ts = sb[0] + sb[2] + sb[4] + sb[6];
  float tq = sb[1] + sb[3] + sb[5] + sb[7];
  float mean = ts * (1.f / DIM_);
  float var  = tq * (1.f / DIM_) - mean * mean;
  float rstd = rsqrtf(var + 1e-5f);
  lat[(size_t)eb * DIM_ + tid]       = (v0 - mean) * rstd * gg[e * DIM_ + tid] + bb[e * DIM_ + tid];
  lat[(size_t)eb * DIM_ + tid + 256] = (v1 - mean) * rstd * gg[e * DIM_ + tid + 256] + bb[e * DIM_ + tid + 256];
}

// ------------------------------------- QKV GEMM (two experts: pair*2 + z)
__global__ __launch_bounds__(256) void k_gemm_qkv(
    const bf16_t* __restrict__ h, const bf16_t* __restrict__ wt,
    const float* __restrict__ bias, int pair, int l, bf16_t* __restrict__ qb,
    bf16_t* __restrict__ kb, bf16_t* __restrict__ vb) {
  __shared__ bf16_t As[128 * 32], Bs[128 * 32];
  int esub = blockIdx.z, e = pair * 2 + esub;
  size_t slice = (size_t)esub * QKV_SLICE;
  const bf16_t* A  = h + ((size_t)e * MP + blockIdx.x * 128) * DIM_;
  const bf16_t* Bm = wt + ((size_t)(e * DEPTH_ + l) * (3 * DIM_) + blockIdx.y * 128) * DIM_;
  const float* bp = bias + (size_t)(e * DEPTH_ + l) * (3 * DIM_);
  f32x4v acc[4][4] = {};
  gemm_core(A, Bm, DIM_, As, Bs, acc);
  EPI_SETUP();
#pragma unroll
  for (int mt = 0; mt < 4; mt++)
#pragma unroll
    for (int nt = 0; nt < 4; nt++)
#pragma unroll
      for (int r = 0; r < 4; r++) {
        int row = rb + mt * 16 + r;
        if (row < MROWS) {
          int col = cb + nt * 16;
          float v = acc[mt][nt][r] + bp[col];
          int b = row / S_, s = row - b * S_;
          int which = col >> 9, d = col & 511;
          int hh = d >> 6, dh = d & 63;
          size_t bh = (size_t)b * H_ + hh;
          bf16_t bv = (bf16_t)v;
          if (which == 0)      qb[slice + (bh * SP + s) * DH_ + dh] = bv;
          else if (which == 1) kb[slice + (bh * SP + s) * DH_ + dh] = bv;
          else                 vb[slice + bh * DH_ * SP + (size_t)dh * SP + s] = bv;  // V^T
        }
      }
}

// --------------------------------- flash attention (two experts per launch)
// block = (qt128, head, esub*8+b); 4 waves, each owns 32 q-rows (R4 geometry:
// 9x8x16 = 1152 blocks -- R5 showed smaller tiles double the K/V VMEM
// transaction count and regress). K/V tiles (64x64) staged cooperatively into
// LDS via global_load_lds (lane-contiguous 1KB per instr, ONCE per block):
// ~8x fewer cache-line transactions than 4-wave-redundant direct strided
// loads -- R5's post-mortem shows transactions, not latency, is the limiter.
// Double-buffered: stage kt+1 right after the barrier, compute kt.
// XOR-swizzled chunk layout (slot ch = (p&7)^(row&7)) spreads the 16-row b128
// fragment reads over all bank groups (global_load_lds forbids padding).
// No max-subtraction: scores structurally tiny (|s| <~ 2) so p = exp2(s*c)
// can't overflow fp32; rowsum via ones-MFMA. P transits per-wave LDS
// (stride 72) for C-layout -> A-layout; same-wave LDS is in-order.
__global__ __launch_bounds__(256, 3) void k_attn(const bf16_t* __restrict__ qb,
                                                 const bf16_t* __restrict__ kb,
                                                 const bf16_t* __restrict__ vb,
                                                 int pair, bf16_t* __restrict__ ob) {
  __shared__ bf16_t P[4][32 * 72];
  __shared__ bf16_t Ks[2][4096], Vs[2][4096];
  int qt = blockIdx.x, hh = blockIdx.y;
  int esub = blockIdx.z >> 3, b = blockIdx.z & 7;
  int e = pair * 2 + esub;
  size_t slice = (size_t)esub * QKV_SLICE;
  size_t bh = (size_t)b * H_ + hh;
  const bf16_t* Q = qb + slice + bh * SP * DH_;
  const bf16_t* K = kb + slice + bh * SP * DH_;
  const bf16_t* V = vb + slice + bh * DH_ * SP;
  int lane = threadIdx.x & 63, wave = threadIdx.x >> 6;
  int fr = lane & 15, q4 = lane >> 4;
  int sw = fr & 7;                  // per-lane read-side swizzle
  bf16_t* Pw = &P[wave][0];

  // stage one 64x64 K tile + V tile (rows = key idx / dh; 8 chunks of 8 elems
  // per row). lds chunk p <- global (row=p>>3, ch=(p&7)^(row&7)).
  auto stage = [&](int buf, int ks) {
#pragma unroll
    for (int c = 0; c < 2; c++) {
      int p = c * 256 + wave * 64 + lane;
      int row = p >> 3;
      int ch = (p & 7) ^ (row & 7);
      bf16_t* lk = &Ks[buf][(c * 256 + wave * 64) * 8];  // wave-uniform base
      bf16_t* lv = &Vs[buf][(c * 256 + wave * 64) * 8];
      async16(K + (size_t)(ks + row) * DH_ + ch * 8, lk);
      async16(V + (size_t)row * SP + ks + ch * 8, lv);
    }
  };

  bf16x8v qf[2][2];
#pragma unroll
  for (int mt = 0; mt < 2; mt++)
#pragma unroll
    for (int kk = 0; kk < 2; kk++)
      qf[mt][kk] = *(const bf16x8v*)&Q[(size_t)(qt * 128 + wave * 32 + mt * 16 + fr) * DH_
                                       + q4 * 8 + kk * 32];

  bf16x8v ones;
#pragma unroll
  for (int j = 0; j < 8; j++) ones[j] = (bf16_t)1.0f;

  f32x4v O[2][4] = {};
  f32x4v lacc[2] = {};

  const float cl2e = 0.125f * 1.4426950408889634f;  // DH^-0.5 * log2(e)

  stage(0, 0);
  for (int kt = 0; kt < 17; kt++) {
    int cur = kt & 1, ks = kt * 64;
    __syncthreads();                 // vmcnt drain: buf[cur] staged & visible
    if (kt < 16) stage(1 - cur, ks + 64);  // in flight across this compute
    const bf16_t* Kb = &Ks[cur][0];
    const bf16_t* Vb = &Vs[cur][0];
    f32x4v sc[2][4] = {};
#pragma unroll
    for (int nt = 0; nt < 4; nt++) {
      int rbase = (nt * 16 + fr) * 8;
      bf16x8v kf0 = *(const bf16x8v*)&Kb[(rbase + ((q4 + 0) ^ sw)) * 8];
      bf16x8v kf1 = *(const bf16x8v*)&Kb[(rbase + ((q4 + 4) ^ sw)) * 8];
#pragma unroll
      for (int mt = 0; mt < 2; mt++) {
        sc[mt][nt] = MFMA(qf[mt][0], kf0, sc[mt][nt]);
        sc[mt][nt] = MFMA(qf[mt][1], kf1, sc[mt][nt]);
      }
    }
    // mask invalid key columns (only last tile; forces p=0 there)
    if (ks + 64 > S_) {
#pragma unroll
      for (int nt = 0; nt < 4; nt++)
        if (ks + nt * 16 + fr >= S_) {
#pragma unroll
          for (int mt = 0; mt < 2; mt++)
#pragma unroll
            for (int c = 0; c < 4; c++) sc[mt][nt][c] = -1e30f;
        }
    }
    // p = exp2(s * c); write straight to per-wave LDS in C layout
#pragma unroll
    for (int mt = 0; mt < 2; mt++)
#pragma unroll
      for (int nt = 0; nt < 4; nt++)
#pragma unroll
        for (int c = 0; c < 4; c++) {
          float p = exp2f(sc[mt][nt][c] * cl2e);
          Pw[(mt * 16 + q4 * 4 + c) * 72 + nt * 16 + fr] = (bf16_t)p;
        }
    // P @ V and P @ ones (rowsum) -- same-wave LDS write->read is in-order
#pragma unroll
    for (int kk = 0; kk < 2; kk++) {
      bf16x8v pa[2];
#pragma unroll
      for (int mt = 0; mt < 2; mt++) {
        pa[mt] = *(const bf16x8v*)&Pw[(mt * 16 + fr) * 72 + q4 * 8 + kk * 32];
        lacc[mt] = MFMA(pa[mt], ones, lacc[mt]);
      }
#pragma unroll
      for (int nt = 0; nt < 4; nt++) {
        bf16x8v vf = *(const bf16x8v*)&Vb[((nt * 16 + fr) * 8 + ((q4 + kk * 4) ^ sw)) * 8];
#pragma unroll
        for (int mt = 0; mt < 2; mt++)
          O[mt][nt] = MFMA(pa[mt], vf, O[mt][nt]);
      }
    }
  }
#pragma unroll
  for (int mt = 0; mt < 2; mt++)
#pragma unroll
    for (int c = 0; c < 4; c++) {
      int s = qt * 128 + wave * 32 + mt * 16 + q4 * 4 + c;
      if (s < S_) {
        float inv = 1.f / lacc[mt][c];
#pragma unroll
        for (int nt = 0; nt < 4; nt++)
          ob[((size_t)e * MP + (size_t)b * S_ + s) * DIM_ + hh * DH_ + nt * 16 + fr]
              = (bf16_t)(O[mt][nt][c] * inv);
      }
    }
}

// ------------------------------------------- GEMM + residual-add (Wo and W2)
__global__ __launch_bounds__(256) void k_gemm_res(
    const bf16_t* __restrict__ abuf, const bf16_t* __restrict__ wt,
    const float* __restrict__ bias, int l, float* __restrict__ t) {
  __shared__ bf16_t As[128 * 32], Bs[128 * 32];
  int e = blockIdx.z;
  const bf16_t* A  = abuf + ((size_t)e * MP + blockIdx.x * 128) * DIM_;
  const bf16_t* Bm = wt + ((size_t)(e * DEPTH_ + l) * DIM_ + blockIdx.y * 128) * DIM_;
  const float* bp = bias + (size_t)(e * DEPTH_ + l) * DIM_;
  f32x4v acc[4][4] = {};
  gemm_core(A, Bm, DIM_, As, Bs, acc);
  EPI_SETUP();
#pragma unroll
  for (int mt = 0; mt < 4; mt++)
#pragma unroll
    for (int nt = 0; nt < 4; nt++)
#pragma unroll
      for (int r = 0; r < 4; r++) {
        int row = rb + mt * 16 + r;
        if (row < MROWS) {
          int col = cb + nt * 16;
          t[((size_t)e * MROWS + row) * DIM_ + col] += acc[mt][nt][r] + bp[col];
        }
      }
}

// ----------------------------------------------------------- W1 GEMM + gelu
__global__ __launch_bounds__(256) void k_gemm_gelu(
    const bf16_t* __restrict__ abuf, const bf16_t* __restrict__ wt,
    const float* __restrict__ bias, int l, bf16_t* __restrict__ ub) {
  __shared__ bf16_t As[128 * 32], Bs[128 * 32];
  int e = blockIdx.z;
  const bf16_t* A  = abuf + ((size_t)e * MP + blockIdx.x * 128) * DIM_;
  const bf16_t* Bm = wt + ((size_t)(e * DEPTH_ + l) * DIM_ + blockIdx.y * 128) * DIM_;
  const float* bp = bias + (size_t)(e * DEPTH_ + l) * DIM_;
  f32x4v acc[4][4] = {};
  gemm_core(A, Bm, DIM_, As, Bs, acc);
  EPI_SETUP();
#pragma unroll
  for (int mt = 0; mt < 4; mt++)
#pragma unroll
    for (int nt = 0; nt < 4; nt++)
#pragma unroll
      for (int r = 0; r < 4; r++) {
        int row = rb + mt * 16 + r;
        if (row < MROWS) {
          int col = cb + nt * 16;
          float v = acc[mt][nt][r] + bp[col];
          // jax.nn.gelu default (approximate=True, tanh form)
          float u = 0.7978845608028654f * (v + 0.044715f * v * v * v);
          float g = 0.5f * v * (1.f + tanhf(u));
          ub[((size_t)e * MP + row) * DIM_ + col] = (bf16_t)g;
        }
      }
}

// ---------------------------------------------------------- head + mixtures
__global__ __launch_bounds__(256) void k_head(const float* __restrict__ lat,
                                              const float* __restrict__ Wh,
                                              const float* __restrict__ bh,
                                              const float* __restrict__ gws,
                                              float* __restrict__ out) {
  int b = blockIdx.x, tid = threadIdx.x;
  for (int d = tid; d < DIM_; d += 256) {
    float a = 0.f;
#pragma unroll
    for (int e = 0; e < 4; e++)
      a += gws[b * 4 + e] * lat[(size_t)(e * B_ + b) * DIM_ + d];
    out[b * DIM_ + d] = a;
  }
  __shared__ float lg[4][10];
  if (tid < 40) {
    int e = tid / 10, c = tid % 10;
    const float* le = lat + (size_t)(e * B_ + b) * DIM_;
    const float* w  = Wh + (size_t)e * DIM_ * C_;
    float a = 0.f;
    for (int d = 0; d < DIM_; d++) a += le[d] * w[d * C_ + c];
    lg[e][c] = a + bh[e * C_ + c];
  }
  __syncthreads();
  if (tid < 10) {
    float a = 0.f;
#pragma unroll
    for (int e = 0; e < 4; e++) a += gws[b * 4 + e] * lg[e][tid];
    out[B_ * DIM_ + b * C_ + tid] = a;
  }
}

// ------------------------------------------------------------------- launch
extern "C" void kernel_launch(void* const* d_in, const int* in_sizes, int n_in,
                              void* d_out, int out_size, void* d_ws, size_t ws_size,
                              hipStream_t stream) {
  const float* x    = (const float*)d_in[0];
  const float* Wr   = (const float*)d_in[1];
  const float* br   = (const float*)d_in[2];
  const float* Wrf  = (const float*)d_in[3];
  const float* brf  = (const float*)d_in[4];
  const float* Wp   = (const float*)d_in[5];
  const float* bp   = (const float*)d_in[6];
  const float* cls  = (const float*)d_in[7];
  const float* ln1g = (const float*)d_in[8];
  const float* ln1b = (const float*)d_in[9];
  const float* Wqkv = (const float*)d_in[10];
  const float* bqkv = (const float*)d_in[11];
  const float* Wo   = (const float*)d_in[12];
  const float* bo   = (const float*)d_in[13];
  const float* ln2g = (const float*)d_in[14];
  const float* ln2b = (const float*)d_in[15];
  const float* W1   = (const float*)d_in[16];
  const float* b1   = (const float*)d_in[17];
  const float* W2   = (const float*)d_in[18];
  const float* b2   = (const float*)d_in[19];
  const float* lnfg = (const float*)d_in[20];
  const float* lnfb = (const float*)d_in[21];
  const float* Wh   = (const float*)d_in[22];
  const float* bh   = (const float*)d_in[23];
  float* out = (float*)d_out;

  // ---- workspace layout (~210 MiB total; stream-ordered aliasing) ----
  char* w = (char*)d_ws;
  size_t off = 0;
  auto take = [&](size_t bytes) {
    void* p = w + off;
    off += (bytes + 255) & ~(size_t)255;
    return p;
  };
  // persistent region (~153 MiB)
  bf16_t* wqkv_t = (bf16_t*)take((size_t)E_ * DEPTH_ * 3 * DIM_ * DIM_ * 2);
  bf16_t* wo_t   = (bf16_t*)take((size_t)E_ * DEPTH_ * DIM_ * DIM_ * 2);
  bf16_t* w1_t   = (bf16_t*)take((size_t)E_ * DEPTH_ * DIM_ * DIM_ * 2);
  bf16_t* w2_t   = (bf16_t*)take((size_t)E_ * DEPTH_ * DIM_ * DIM_ * 2);
  float*  tbuf   = (float*)take((size_t)E_ * MROWS * DIM_ * 4);
  bf16_t* hbuf   = (bf16_t*)take((size_t)E_ * MP * DIM_ * 2);
  bf16_t* obuf   = (bf16_t*)take((size_t)E_ * MP * DIM_ * 2);  // attn out / W1 out
  float*  racc   = (float*)take((size_t)B_ * DIM_ * 4);
  float*  gws    = (float*)take((size_t)B_ * E_ * 4);
  float*  late   = (float*)take((size_t)E_ * B_ * DIM_ * 4);
  // union region (max of pre-loop view A=44 MiB, loop view B=57 MiB)
  char* uni = (char*)w + off;
  //   view A (dead after k_gemm_proj):
  bf16_t* x_bf = (bf16_t*)(uni);
  bf16_t* wr_t = (bf16_t*)(uni + (size_t)8192 * IN_ * 2);
  bf16_t* wp_t = (bf16_t*)(uni + (size_t)8192 * IN_ * 2 + (size_t)DIM_ * IN_ * 2);
  //   view B (2-expert q/k/v, rewritten every (l,pair)):
  size_t qkv2 = 2 * QKV_SLICE * 2;  // two experts, bytes
  bf16_t* qbuf = (bf16_t*)(uni);
  bf16_t* kbuf = (bf16_t*)(uni + qkv2);
  bf16_t* vbuf = (bf16_t*)(uni + 2 * qkv2);
  (void)in_sizes; (void)n_in; (void)out_size; (void)ws_size;

  // input + weight conversion (weights transposed to [N][K] bf16)
  int n4 = 8192 * IN_ / 4;
  k_cvt<<<(n4 + 255) / 256, 256, 0, stream>>>(x, x_bf, n4);
  dim3 tb(32, 8);
  k_tcvt<<<dim3(DIM_ / 32, IN_ / 32, 1), tb, 0, stream>>>(Wr, wr_t, IN_, DIM_);
  k_tcvt<<<dim3(DIM_ / 32, IN_ / 32, E_), tb, 0, stream>>>(Wp, wp_t, IN_, DIM_);
  k_tcvt<<<dim3(3 * DIM_ / 32, DIM_ / 32, E_ * DEPTH_), tb, 0, stream>>>(Wqkv, wqkv_t, DIM_, 3 * DIM_);
  k_tcvt<<<dim3(DIM_ / 32, DIM_ / 32, E_ * DEPTH_), tb, 0, stream>>>(Wo, wo_t, DIM_, DIM_);
  k_tcvt<<<dim3(DIM_ / 32, DIM_ / 32, E_ * DEPTH_), tb, 0, stream>>>(W1, w1_t, DIM_, DIM_);
  k_tcvt<<<dim3(DIM_ / 32, DIM_ / 32, E_ * DEPTH_), tb, 0, stream>>>(W2, w2_t, DIM_, DIM_);

  // router + expert input projections (z=0 router-pool, z=1..4 experts)
  hipMemsetAsync(racc, 0, (size_t)B_ * DIM_ * 4, stream);
  k_gemm_proj<<<dim3(64, 4, 5), 256, 0, stream>>>(x_bf, wr_t, wp_t, br, bp, racc, tbuf);
  k_cls<<<32, 512, 0, stream>>>(cls, tbuf);
  k_router<<<1, 64, 0, stream>>>(racc, Wrf, brf, gws, out + B_ * DIM_ + B_ * C_);

  for (int l = 0; l < DEPTH_; l++) {
    k_ln<<<dim3(S_, B_, E_), 256, 0, stream>>>(tbuf, ln1g, ln1b, l, hbuf);
    for (int pair = 0; pair < 2; pair++) {
      k_gemm_qkv<<<dim3(65, 12, 2), 256, 0, stream>>>(hbuf, wqkv_t, bqkv, pair, l, qbuf, kbuf, vbuf);
      k_attn<<<dim3(9, H_, 16), 256, 0, stream>>>(qbuf, kbuf, vbuf, pair, obuf);
    }
    k_gemm_res<<<dim3(65, 4, E_), 256, 0, stream>>>(obuf, wo_t, bo, l, tbuf);
    k_ln<<<dim3(S_, B_, E_), 256, 0, stream>>>(tbuf, ln2g, ln2b, l, hbuf);
    k_gemm_gelu<<<dim3(65, 4, E_), 256, 0, stream>>>(hbuf, w1_t, b1, l, obuf);
    k_gemm_res<<<dim3(65, 4, E_), 256, 0, stream>>>(obuf, w2_t, b2, l, tbuf);
  }
  k_lnf<<<32, 256, 0, stream>>>(tbuf, lnfg, lnfb, late);
  k_head<<<8, 256, 0, stream>>>(late, Wh, bh, gws, out);
}

// Round 7
// 1549.683 us; speedup vs baseline: 1.5458x; 1.0077x over previous
//
#include <hip/hip_runtime.h>
#include <hip/hip_bf16.h>
#include <math.h>

typedef __bf16 bf16_t;
typedef __bf16 bf16x4v __attribute__((ext_vector_type(4)));
typedef __bf16 bf16x8v __attribute__((ext_vector_type(8)));
typedef float  f32x4v  __attribute__((ext_vector_type(4)));

#define MFMA(a,b,c) __builtin_amdgcn_mfma_f32_16x16x32_bf16(a,b,c,0,0,0)

constexpr int B_ = 8, N_ = 1024, IN_ = 2048, DIM_ = 512, H_ = 8, DH_ = 64;
constexpr int DEPTH_ = 2, E_ = 4, C_ = 10, S_ = 1025;
constexpr int SP = 1152;        // padded seq len for q/k/v buffers (9*128)
constexpr int MP = 8320;        // padded row count for activations (65*128)
constexpr int MROWS = B_ * S_;  // 8200 valid rows per expert
constexpr size_t QKV_SLICE = (size_t)B_ * H_ * SP * DH_;  // one expert's q (or k/v)

// ---------------------------------------------------------------- async copy
__device__ __forceinline__ void async16(const void* g, void* l) {
  __builtin_amdgcn_global_load_lds((const __attribute__((address_space(1))) void*)g,
                                   (__attribute__((address_space(3))) void*)l, 16, 0, 0);
}

// ------------------------------------------------------- shared GEMM mainloop
// C[128x128] tile = A[128xK] * B^T[128xK]^T.  Both operands stored [rows][K]
// (weights pre-transposed). 4 waves in 2x2; each wave 64x64 via 4x4 MFMAs.
// LDS chunk-rotation swizzle: slot s of row R holds global 16B chunk
// (s - (R>>1)) & 3.  Un-swizzled reads hit only 8/32 banks per 16-lane
// quarter (R6: 1.05e7 SQ_LDS_BANK_CONFLICT = +4 cyc/ds_read_b128); rotated
// reads cover all 32 banks -> conflict-free.  Stage side is a permutation
// within each row's 64B, so global coalescing is unchanged; rows of the two
// staging instrs differ by 16 (== 0 mod 8) so both use the same chunk.
__device__ __forceinline__ void gemm_core(const bf16_t* __restrict__ A,
                                          const bf16_t* __restrict__ Bm, int K,
                                          bf16_t* As, bf16_t* Bs,
                                          f32x4v acc[4][4]) {
  const int tid  = threadIdx.x;
  const int lane = tid & 63, wave = tid >> 6;
  const int fr = lane & 15, q4 = lane >> 4;
  const int wm = (wave >> 1) * 64, wn = (wave & 1) * 64;
  // staging: wave w fills rows [w*32, w*32+32) of both tiles
  const int srow = wave * 32 + (lane >> 2);
  const int scol = (((lane & 3) - (lane >> 3)) & 3) * 8;   // swizzled chunk
  const int sl   = ((q4 + (fr >> 1)) & 3) * 8;             // read-side slot
  const bf16_t* ga = A  + (size_t)srow * K + scol;
  const bf16_t* gb = Bm + (size_t)srow * K + scol;
  bf16_t* la = As + wave * 1024;  // wave-uniform LDS base; HW adds lane*16B
  bf16_t* lb = Bs + wave * 1024;
  for (int k0 = 0; k0 < K; k0 += 32) {
    async16(ga + k0,          la);
    async16(ga + k0 + 16 * K, la + 512);
    async16(gb + k0,          lb);
    async16(gb + k0 + 16 * K, lb + 512);
    __syncthreads();   // drains vmcnt(0): staged data visible
    bf16x8v af[4], bfr[4];
#pragma unroll
    for (int mt = 0; mt < 4; mt++)
      af[mt] = *(const bf16x8v*)&As[(wm + mt * 16 + fr) * 32 + sl];
#pragma unroll
    for (int nt = 0; nt < 4; nt++)
      bfr[nt] = *(const bf16x8v*)&Bs[(wn + nt * 16 + fr) * 32 + sl];
#pragma unroll
    for (int mt = 0; mt < 4; mt++)
#pragma unroll
      for (int nt = 0; nt < 4; nt++)
        acc[mt][nt] = MFMA(af[mt], bfr[nt], acc[mt][nt]);
    __syncthreads();   // all reads done before next stage overwrites
  }
}

// epilogue index helper: global row/col base for (mt,nt,r) iteration
#define EPI_SETUP()                                                    \
  int lane = threadIdx.x & 63, wave = threadIdx.x >> 6;                \
  int rb = blockIdx.x * 128 + (wave >> 1) * 64 + ((lane >> 4) << 2);   \
  int cb = blockIdx.y * 128 + (wave & 1) * 64 + (lane & 15);

// ----------------------------------------------------------------- converts
__global__ __launch_bounds__(256) void k_cvt(const float* __restrict__ in,
                                             bf16_t* __restrict__ out, int n4) {
  int i = blockIdx.x * blockDim.x + threadIdx.x;
  if (i < n4) {
    float4 v = ((const float4*)in)[i];
    bf16x4v o = {(bf16_t)v.x, (bf16_t)v.y, (bf16_t)v.z, (bf16_t)v.w};
    ((bf16x4v*)out)[i] = o;
  }
}

// in [nmat][K][N] f32 -> out [nmat][N][K] bf16 (K,N multiples of 32)
__global__ __launch_bounds__(256) void k_tcvt(const float* __restrict__ in,
                                              bf16_t* __restrict__ out, int K, int N) {
  __shared__ float tile[32][33];
  size_t mb = (size_t)blockIdx.z * K * N;
  int k0 = blockIdx.y * 32, n0 = blockIdx.x * 32;
  int tx = threadIdx.x, ty = threadIdx.y;
#pragma unroll
  for (int i = 0; i < 32; i += 8)
    tile[ty + i][tx] = in[mb + (size_t)(k0 + ty + i) * N + n0 + tx];
  __syncthreads();
#pragma unroll
  for (int i = 0; i < 32; i += 8)
    out[mb + (size_t)(n0 + ty + i) * K + k0 + tx] = (bf16_t)tile[tx][ty + i];
}

// ------------------------------------------------- proj GEMM (router+experts)
// z=0: router relu -> atomic mean-pool partials into racc[B][DIM]
// z=1..4: expert relu -> t[e][b][1+n][d]
__global__ __launch_bounds__(256) void k_gemm_proj(
    const bf16_t* __restrict__ xbf, const bf16_t* __restrict__ wrt,
    const bf16_t* __restrict__ wpt, const float* __restrict__ br,
    const float* __restrict__ bp, float* __restrict__ racc,
    float* __restrict__ t) {
  __shared__ bf16_t As[128 * 32], Bs[128 * 32];
  int z = blockIdx.z;
  const bf16_t* A  = xbf + (size_t)blockIdx.x * 128 * IN_;
  const bf16_t* Bm = (z == 0 ? wrt : wpt + (size_t)(z - 1) * DIM_ * IN_)
                     + (size_t)blockIdx.y * 128 * IN_;
  const float* bias = (z == 0) ? br : bp + (z - 1) * DIM_;
  f32x4v acc[4][4] = {};
  gemm_core(A, Bm, IN_, As, Bs, acc);
  EPI_SETUP();
  if (z == 0) {
    // all 128 rows of this block belong to batch b = blockIdx.x>>3
    int b = blockIdx.x >> 3;
    float part[4] = {0.f, 0.f, 0.f, 0.f};
#pragma unroll
    for (int mt = 0; mt < 4; mt++)
#pragma unroll
      for (int nt = 0; nt < 4; nt++)
#pragma unroll
        for (int r = 0; r < 4; r++)
          part[nt] += fmaxf(acc[mt][nt][r] + bias[cb + nt * 16], 0.f);
#pragma unroll
    for (int nt = 0; nt < 4; nt++)
      atomicAdd(&racc[b * DIM_ + cb + nt * 16], part[nt]);
  } else {
    int e = z - 1;
#pragma unroll
    for (int mt = 0; mt < 4; mt++)
#pragma unroll
      for (int nt = 0; nt < 4; nt++)
#pragma unroll
        for (int r = 0; r < 4; r++) {
          int row = rb + mt * 16 + r, col = cb + nt * 16;
          float v = fmaxf(acc[mt][nt][r] + bias[col], 0.f);
          int b = row >> 10, n = row & 1023;
          t[((size_t)(e * B_ + b) * S_ + 1 + n) * DIM_ + col] = v;
        }
  }
}

__global__ __launch_bounds__(512) void k_cls(const float* __restrict__ cls,
                                             float* __restrict__ t) {
  // block = (e*8+b); s=0 row
  t[(size_t)blockIdx.x * S_ * DIM_ + threadIdx.x] =
      cls[(blockIdx.x >> 3) * DIM_ + threadIdx.x];
}

// ------------------------------------------------------------------ router
__global__ __launch_bounds__(64) void k_router(const float* __restrict__ racc,
                                               const float* __restrict__ Wrf,
                                               const float* __restrict__ brf,
                                               float* __restrict__ gws,
                                               float* __restrict__ outg) {
  __shared__ float lg[8][4];
  int t = threadIdx.x;
  if (t < 32) {
    int b = t >> 2, e = t & 3;
    const float* r = racc + b * DIM_;
    float a = 0.f;
    for (int d = 0; d < DIM_; d++) a += r[d] * Wrf[d * 4 + e];
    lg[b][e] = a * (1.f / N_) + brf[e];
  }
  __syncthreads();
  if (t < 8) {
    int b = t;
    float mx = fmaxf(fmaxf(lg[b][0], lg[b][1]), fmaxf(lg[b][2], lg[b][3]));
    float s = 0.f, g[4];
#pragma unroll
    for (int e = 0; e < 4; e++) { g[e] = __expf(lg[b][e] - mx); s += g[e]; }
#pragma unroll
    for (int e = 0; e < 4; e++) {
      float gv = g[e] / s;
      gws[b * 4 + e] = gv;
      outg[b * 4 + e] = gv;
    }
  }
}

// --------------------------------------------------------------- layernorms
__global__ __launch_bounds__(256) void k_ln(const float* __restrict__ t,
                                            const float* __restrict__ gg,
                                            const float* __restrict__ bb, int l,
                                            bf16_t* __restrict__ h) {
  int s = blockIdx.x, b = blockIdx.y, e = blockIdx.z;
  const float* row = t + ((size_t)(e * B_ + b) * S_ + s) * DIM_;
  int tid = threadIdx.x;
  float v0 = row[tid], v1 = row[tid + 256];
  float sum = v0 + v1, sq = v0 * v0 + v1 * v1;
  for (int o = 32; o > 0; o >>= 1) {
    sum += __shfl_down(sum, o, 64);
    sq  += __shfl_down(sq, o, 64);
  }
  __shared__ float sb[8];
  int lane = tid & 63, wave = tid >> 6;
  if (lane == 0) { sb[wave * 2] = sum; sb[wave * 2 + 1] = sq; }
  __syncthreads();
  float ts = sb[0] + sb[2] + sb[4] + sb[6];
  float tq = sb[1] + sb[3] + sb[5] + sb[7];
  float mean = ts * (1.f / DIM_);
  float var  = tq * (1.f / DIM_) - mean * mean;
  float rstd = rsqrtf(var + 1e-5f);
  const float* gp = gg + (size_t)(e * DEPTH_ + l) * DIM_;
  const float* bp = bb + (size_t)(e * DEPTH_ + l) * DIM_;
  bf16_t* orow = h + ((size_t)e * MP + (size_t)b * S_ + s) * DIM_;
  orow[tid]       = (bf16_t)((v0 - mean) * rstd * gp[tid] + bp[tid]);
  orow[tid + 256] = (bf16_t)((v1 - mean) * rstd * gp[tid + 256] + bp[tid + 256]);
}

__global__ __launch_bounds__(256) void k_lnf(const float* __restrict__ t,
                                             const float* __restrict__ gg,
                                             const float* __restrict__ bb,
                                             float* __restrict__ lat) {
  int eb = blockIdx.x, e = eb >> 3;
  const float* row = t + (size_t)eb * S_ * DIM_;  // s=0 (cls)
  int tid = threadIdx.x;
  float v0 = row[tid], v1 = row[tid + 256];
  float sum = v0 + v1, sq = v0 * v0 + v1 * v1;
  for (int o = 32; o > 0; o >>= 1) {
    sum += __shfl_down(sum, o, 64);
    sq  += __shfl_down(sq, o, 64);
  }
  __shared__ float sb[8];
  int lane = tid & 63, wave = tid >> 6;
  if (lane == 0) { sb[wave * 2] = sum; sb[wave * 2 + 1] = sq; }
  __syncthreads();
  float ts = sb[0] + sb[2] + sb[4] + sb[6];
  float tq = sb[1] + sb[3] + sb[5] + sb[7];
  float mean = ts * (1.f / DIM_);
  float var  = tq * (1.f / DIM_) - mean * mean;
  float rstd = rsqrtf(var + 1e-5f);
  lat[(size_t)eb * DIM_ + tid]       = (v0 - mean) * rstd * gg[e * DIM_ + tid] + bb[e * DIM_ + tid];
  lat[(size_t)eb * DIM_ + tid + 256] = (v1 - mean) * rstd * gg[e * DIM_ + tid + 256] + bb[e * DIM_ + tid + 256];
}

// ------------------------------------- QKV GEMM (two experts: pair*2 + z)
__global__ __launch_bounds__(256) void k_gemm_qkv(
    const bf16_t* __restrict__ h, const bf16_t* __restrict__ wt,
    const float* __restrict__ bias, int pair, int l, bf16_t* __restrict__ qb,
    bf16_t* __restrict__ kb, bf16_t* __restrict__ vb) {
  __shared__ bf16_t As[128 * 32], Bs[128 * 32];
  int esub = blockIdx.z, e = pair * 2 + esub;
  size_t slice = (size_t)esub * QKV_SLICE;
  const bf16_t* A  = h + ((size_t)e * MP + blockIdx.x * 128) * DIM_;
  const bf16_t* Bm = wt + ((size_t)(e * DEPTH_ + l) * (3 * DIM_) + blockIdx.y * 128) * DIM_;
  const float* bp = bias + (size_t)(e * DEPTH_ + l) * (3 * DIM_);
  f32x4v acc[4][4] = {};
  gemm_core(A, Bm, DIM_, As, Bs, acc);
  EPI_SETUP();
#pragma unroll
  for (int mt = 0; mt < 4; mt++)
#pragma unroll
    for (int nt = 0; nt < 4; nt++)
#pragma unroll
      for (int r = 0; r < 4; r++) {
        int row = rb + mt * 16 + r;
        if (row < MROWS) {
          int col = cb + nt * 16;
          float v = acc[mt][nt][r] + bp[col];
          int b = row / S_, s = row - b * S_;
          int which = col >> 9, d = col & 511;
          int hh = d >> 6, dh = d & 63;
          size_t bh = (size_t)b * H_ + hh;
          bf16_t bv = (bf16_t)v;
          if (which == 0)      qb[slice + (bh * SP + s) * DH_ + dh] = bv;
          else if (which == 1) kb[slice + (bh * SP + s) * DH_ + dh] = bv;
          else                 vb[slice + bh * DH_ * SP + (size_t)dh * SP + s] = bv;  // V^T
        }
      }
}

// --------------------------------- flash attention (two experts per launch)
// block = (qt128, head, esub*8+b); 4 waves, each owns 32 q-rows (R4 geometry:
// 9x8x16 = 1152 blocks -- R5 showed smaller tiles double the K/V VMEM
// transaction count and regress). K/V tiles (64x64) staged cooperatively into
// LDS via global_load_lds (lane-contiguous 1KB per instr, ONCE per block):
// ~8x fewer cache-line transactions than 4-wave-redundant direct strided
// loads. Double-buffered: stage kt+1 right after the barrier, compute kt.
// XOR-swizzled chunk layout (slot ch = (p&7)^(row&7)) spreads the 16-row b128
// fragment reads over all bank groups (global_load_lds forbids padding).
// No max-subtraction: scores structurally tiny (|s| <~ 2) so p = exp2(s*c)
// can't overflow fp32; rowsum via ones-MFMA. P transits per-wave LDS
// (stride 72) for C-layout -> A-layout; same-wave LDS is in-order.
__global__ __launch_bounds__(256, 3) void k_attn(const bf16_t* __restrict__ qb,
                                                 const bf16_t* __restrict__ kb,
                                                 const bf16_t* __restrict__ vb,
                                                 int pair, bf16_t* __restrict__ ob) {
  __shared__ bf16_t P[4][32 * 72];
  __shared__ bf16_t Ks[2][4096], Vs[2][4096];
  int qt = blockIdx.x, hh = blockIdx.y;
  int esub = blockIdx.z >> 3, b = blockIdx.z & 7;
  int e = pair * 2 + esub;
  size_t slice = (size_t)esub * QKV_SLICE;
  size_t bh = (size_t)b * H_ + hh;
  const bf16_t* Q = qb + slice + bh * SP * DH_;
  const bf16_t* K = kb + slice + bh * SP * DH_;
  const bf16_t* V = vb + slice + bh * DH_ * SP;
  int lane = threadIdx.x & 63, wave = threadIdx.x >> 6;
  int fr = lane & 15, q4 = lane >> 4;
  int sw = fr & 7;                  // per-lane read-side swizzle
  bf16_t* Pw = &P[wave][0];

  // stage one 64x64 K tile + V tile (rows = key idx / dh; 8 chunks of 8 elems
  // per row). lds chunk p <- global (row=p>>3, ch=(p&7)^(row&7)).
  auto stage = [&](int buf, int ks) {
#pragma unroll
    for (int c = 0; c < 2; c++) {
      int p = c * 256 + wave * 64 + lane;
      int row = p >> 3;
      int ch = (p & 7) ^ (row & 7);
      bf16_t* lk = &Ks[buf][(c * 256 + wave * 64) * 8];  // wave-uniform base
      bf16_t* lv = &Vs[buf][(c * 256 + wave * 64) * 8];
      async16(K + (size_t)(ks + row) * DH_ + ch * 8, lk);
      async16(V + (size_t)row * SP + ks + ch * 8, lv);
    }
  };

  bf16x8v qf[2][2];
#pragma unroll
  for (int mt = 0; mt < 2; mt++)
#pragma unroll
    for (int kk = 0; kk < 2; kk++)
      qf[mt][kk] = *(const bf16x8v*)&Q[(size_t)(qt * 128 + wave * 32 + mt * 16 + fr) * DH_
                                       + q4 * 8 + kk * 32];

  bf16x8v ones;
#pragma unroll
  for (int j = 0; j < 8; j++) ones[j] = (bf16_t)1.0f;

  f32x4v O[2][4] = {};
  f32x4v lacc[2] = {};

  const float cl2e = 0.125f * 1.4426950408889634f;  // DH^-0.5 * log2(e)

  stage(0, 0);
  for (int kt = 0; kt < 17; kt++) {
    int cur = kt & 1, ks = kt * 64;
    __syncthreads();                 // vmcnt drain: buf[cur] staged & visible
    if (kt < 16) stage(1 - cur, ks + 64);  // in flight across this compute
    const bf16_t* Kb = &Ks[cur][0];
    const bf16_t* Vb = &Vs[cur][0];
    f32x4v sc[2][4] = {};
#pragma unroll
    for (int nt = 0; nt < 4; nt++) {
      int rbase = (nt * 16 + fr) * 8;
      bf16x8v kf0 = *(const bf16x8v*)&Kb[(rbase + ((q4 + 0) ^ sw)) * 8];
      bf16x8v kf1 = *(const bf16x8v*)&Kb[(rbase + ((q4 + 4) ^ sw)) * 8];
#pragma unroll
      for (int mt = 0; mt < 2; mt++) {
        sc[mt][nt] = MFMA(qf[mt][0], kf0, sc[mt][nt]);
        sc[mt][nt] = MFMA(qf[mt][1], kf1, sc[mt][nt]);
      }
    }
    // mask invalid key columns (only last tile; forces p=0 there)
    if (ks + 64 > S_) {
#pragma unroll
      for (int nt = 0; nt < 4; nt++)
        if (ks + nt * 16 + fr >= S_) {
#pragma unroll
          for (int mt = 0; mt < 2; mt++)
#pragma unroll
            for (int c = 0; c < 4; c++) sc[mt][nt][c] = -1e30f;
        }
    }
    // p = exp2(s * c); write straight to per-wave LDS in C layout
#pragma unroll
    for (int mt = 0; mt < 2; mt++)
#pragma unroll
      for (int nt = 0; nt < 4; nt++)
#pragma unroll
        for (int c = 0; c < 4; c++) {
          float p = exp2f(sc[mt][nt][c] * cl2e);
          Pw[(mt * 16 + q4 * 4 + c) * 72 + nt * 16 + fr] = (bf16_t)p;
        }
    // P @ V and P @ ones (rowsum) -- same-wave LDS write->read is in-order
#pragma unroll
    for (int kk = 0; kk < 2; kk++) {
      bf16x8v pa[2];
#pragma unroll
      for (int mt = 0; mt < 2; mt++) {
        pa[mt] = *(const bf16x8v*)&Pw[(mt * 16 + fr) * 72 + q4 * 8 + kk * 32];
        lacc[mt] = MFMA(pa[mt], ones, lacc[mt]);
      }
#pragma unroll
      for (int nt = 0; nt < 4; nt++) {
        bf16x8v vf = *(const bf16x8v*)&Vb[((nt * 16 + fr) * 8 + ((q4 + kk * 4) ^ sw)) * 8];
#pragma unroll
        for (int mt = 0; mt < 2; mt++)
          O[mt][nt] = MFMA(pa[mt], vf, O[mt][nt]);
      }
    }
  }
#pragma unroll
  for (int mt = 0; mt < 2; mt++)
#pragma unroll
    for (int c = 0; c < 4; c++) {
      int s = qt * 128 + wave * 32 + mt * 16 + q4 * 4 + c;
      if (s < S_) {
        float inv = 1.f / lacc[mt][c];
#pragma unroll
        for (int nt = 0; nt < 4; nt++)
          ob[((size_t)e * MP + (size_t)b * S_ + s) * DIM_ + hh * DH_ + nt * 16 + fr]
              = (bf16_t)(O[mt][nt][c] * inv);
      }
    }
}

// ------------------------------------------- GEMM + residual-add (Wo and W2)
__global__ __launch_bounds__(256) void k_gemm_res(
    const bf16_t* __restrict__ abuf, const bf16_t* __restrict__ wt,
    const float* __restrict__ bias, int l, float* __restrict__ t) {
  __shared__ bf16_t As[128 * 32], Bs[128 * 32];
  int e = blockIdx.z;
  const bf16_t* A  = abuf + ((size_t)e * MP + blockIdx.x * 128) * DIM_;
  const bf16_t* Bm = wt + ((size_t)(e * DEPTH_ + l) * DIM_ + blockIdx.y * 128) * DIM_;
  const float* bp = bias + (size_t)(e * DEPTH_ + l) * DIM_;
  f32x4v acc[4][4] = {};
  gemm_core(A, Bm, DIM_, As, Bs, acc);
  EPI_SETUP();
#pragma unroll
  for (int mt = 0; mt < 4; mt++)
#pragma unroll
    for (int nt = 0; nt < 4; nt++)
#pragma unroll
      for (int r = 0; r < 4; r++) {
        int row = rb + mt * 16 + r;
        if (row < MROWS) {
          int col = cb + nt * 16;
          t[((size_t)e * MROWS + row) * DIM_ + col] += acc[mt][nt][r] + bp[col];
        }
      }
}

// ----------------------------------------------------------- W1 GEMM + gelu
__global__ __launch_bounds__(256) void k_gemm_gelu(
    const bf16_t* __restrict__ abuf, const bf16_t* __restrict__ wt,
    const float* __restrict__ bias, int l, bf16_t* __restrict__ ub) {
  __shared__ bf16_t As[128 * 32], Bs[128 * 32];
  int e = blockIdx.z;
  const bf16_t* A  = abuf + ((size_t)e * MP + blockIdx.x * 128) * DIM_;
  const bf16_t* Bm = wt + ((size_t)(e * DEPTH_ + l) * DIM_ + blockIdx.y * 128) * DIM_;
  const float* bp = bias + (size_t)(e * DEPTH_ + l) * DIM_;
  f32x4v acc[4][4] = {};
  gemm_core(A, Bm, DIM_, As, Bs, acc);
  EPI_SETUP();
#pragma unroll
  for (int mt = 0; mt < 4; mt++)
#pragma unroll
    for (int nt = 0; nt < 4; nt++)
#pragma unroll
      for (int r = 0; r < 4; r++) {
        int row = rb + mt * 16 + r;
        if (row < MROWS) {
          int col = cb + nt * 16;
          float v = acc[mt][nt][r] + bp[col];
          // jax.nn.gelu tanh form; tanh(u) = 1 - 2/(exp(2u)+1) via fast exp
          float u2 = __expf(1.5957691216057308f * (v + 0.044715f * v * v * v));
          float th = 1.f - 2.f / (u2 + 1.f);
          float g = 0.5f * v * (1.f + th);
          ub[((size_t)e * MP + row) * DIM_ + col] = (bf16_t)g;
        }
      }
}

// ---------------------------------------------------------- head + mixtures
__global__ __launch_bounds__(256) void k_head(const float* __restrict__ lat,
                                              const float* __restrict__ Wh,
                                              const float* __restrict__ bh,
                                              const float* __restrict__ gws,
                                              float* __restrict__ out) {
  int b = blockIdx.x, tid = threadIdx.x;
  for (int d = tid; d < DIM_; d += 256) {
    float a = 0.f;
#pragma unroll
    for (int e = 0; e < 4; e++)
      a += gws[b * 4 + e] * lat[(size_t)(e * B_ + b) * DIM_ + d];
    out[b * DIM_ + d] = a;
  }
  __shared__ float lg[4][10];
  if (tid < 40) {
    int e = tid / 10, c = tid % 10;
    const float* le = lat + (size_t)(e * B_ + b) * DIM_;
    const float* w  = Wh + (size_t)e * DIM_ * C_;
    float a = 0.f;
    for (int d = 0; d < DIM_; d++) a += le[d] * w[d * C_ + c];
    lg[e][c] = a + bh[e * C_ + c];
  }
  __syncthreads();
  if (tid < 10) {
    float a = 0.f;
#pragma unroll
    for (int e = 0; e < 4; e++) a += gws[b * 4 + e] * lg[e][tid];
    out[B_ * DIM_ + b * C_ + tid] = a;
  }
}

// ------------------------------------------------------------------- launch
extern "C" void kernel_launch(void* const* d_in, const int* in_sizes, int n_in,
                              void* d_out, int out_size, void* d_ws, size_t ws_size,
                              hipStream_t stream) {
  const float* x    = (const float*)d_in[0];
  const float* Wr   = (const float*)d_in[1];
  const float* br   = (const float*)d_in[2];
  const float* Wrf  = (const float*)d_in[3];
  const float* brf  = (const float*)d_in[4];
  const float* Wp   = (const float*)d_in[5];
  const float* bp   = (const float*)d_in[6];
  const float* cls  = (const float*)d_in[7];
  const float* ln1g = (const float*)d_in[8];
  const float* ln1b = (const float*)d_in[9];
  const float* Wqkv = (const float*)d_in[10];
  const float* bqkv = (const float*)d_in[11];
  const float* Wo   = (const float*)d_in[12];
  const float* bo   = (const float*)d_in[13];
  const float* ln2g = (const float*)d_in[14];
  const float* ln2b = (const float*)d_in[15];
  const float* W1   = (const float*)d_in[16];
  const float* b1   = (const float*)d_in[17];
  const float* W2   = (const float*)d_in[18];
  const float* b2   = (const float*)d_in[19];
  const float* lnfg = (const float*)d_in[20];
  const float* lnfb = (const float*)d_in[21];
  const float* Wh   = (const float*)d_in[22];
  const float* bh   = (const float*)d_in[23];
  float* out = (float*)d_out;

  // ---- workspace layout (~210 MiB total; stream-ordered aliasing) ----
  char* w = (char*)d_ws;
  size_t off = 0;
  auto take = [&](size_t bytes) {
    void* p = w + off;
    off += (bytes + 255) & ~(size_t)255;
    return p;
  };
  // persistent region (~153 MiB)
  bf16_t* wqkv_t = (bf16_t*)take((size_t)E_ * DEPTH_ * 3 * DIM_ * DIM_ * 2);
  bf16_t* wo_t   = (bf16_t*)take((size_t)E_ * DEPTH_ * DIM_ * DIM_ * 2);
  bf16_t* w1_t   = (bf16_t*)take((size_t)E_ * DEPTH_ * DIM_ * DIM_ * 2);
  bf16_t* w2_t   = (bf16_t*)take((size_t)E_ * DEPTH_ * DIM_ * DIM_ * 2);
  float*  tbuf   = (float*)take((size_t)E_ * MROWS * DIM_ * 4);
  bf16_t* hbuf   = (bf16_t*)take((size_t)E_ * MP * DIM_ * 2);
  bf16_t* obuf   = (bf16_t*)take((size_t)E_ * MP * DIM_ * 2);  // attn out / W1 out
  float*  racc   = (float*)take((size_t)B_ * DIM_ * 4);
  float*  gws    = (float*)take((size_t)B_ * E_ * 4);
  float*  late   = (float*)take((size_t)E_ * B_ * DIM_ * 4);
  // union region (max of pre-loop view A=44 MiB, loop view B=57 MiB)
  char* uni = (char*)w + off;
  //   view A (dead after k_gemm_proj):
  bf16_t* x_bf = (bf16_t*)(uni);
  bf16_t* wr_t = (bf16_t*)(uni + (size_t)8192 * IN_ * 2);
  bf16_t* wp_t = (bf16_t*)(uni + (size_t)8192 * IN_ * 2 + (size_t)DIM_ * IN_ * 2);
  //   view B (2-expert q/k/v, rewritten every (l,pair)):
  size_t qkv2 = 2 * QKV_SLICE * 2;  // two experts, bytes
  bf16_t* qbuf = (bf16_t*)(uni);
  bf16_t* kbuf = (bf16_t*)(uni + qkv2);
  bf16_t* vbuf = (bf16_t*)(uni + 2 * qkv2);
  (void)in_sizes; (void)n_in; (void)out_size; (void)ws_size;

  // input + weight conversion (weights transposed to [N][K] bf16)
  int n4 = 8192 * IN_ / 4;
  k_cvt<<<(n4 + 255) / 256, 256, 0, stream>>>(x, x_bf, n4);
  dim3 tb(32, 8);
  k_tcvt<<<dim3(DIM_ / 32, IN_ / 32, 1), tb, 0, stream>>>(Wr, wr_t, IN_, DIM_);
  k_tcvt<<<dim3(DIM_ / 32, IN_ / 32, E_), tb, 0, stream>>>(Wp, wp_t, IN_, DIM_);
  k_tcvt<<<dim3(3 * DIM_ / 32, DIM_ / 32, E_ * DEPTH_), tb, 0, stream>>>(Wqkv, wqkv_t, DIM_, 3 * DIM_);
  k_tcvt<<<dim3(DIM_ / 32, DIM_ / 32, E_ * DEPTH_), tb, 0, stream>>>(Wo, wo_t, DIM_, DIM_);
  k_tcvt<<<dim3(DIM_ / 32, DIM_ / 32, E_ * DEPTH_), tb, 0, stream>>>(W1, w1_t, DIM_, DIM_);
  k_tcvt<<<dim3(DIM_ / 32, DIM_ / 32, E_ * DEPTH_), tb, 0, stream>>>(W2, w2_t, DIM_, DIM_);

  // router + expert input projections (z=0 router-pool, z=1..4 experts)
  hipMemsetAsync(racc, 0, (size_t)B_ * DIM_ * 4, stream);
  k_gemm_proj<<<dim3(64, 4, 5), 256, 0, stream>>>(x_bf, wr_t, wp_t, br, bp, racc, tbuf);
  k_cls<<<32, 512, 0, stream>>>(cls, tbuf);
  k_router<<<1, 64, 0, stream>>>(racc, Wrf, brf, gws, out + B_ * DIM_ + B_ * C_);

  for (int l = 0; l < DEPTH_; l++) {
    k_ln<<<dim3(S_, B_, E_), 256, 0, stream>>>(tbuf, ln1g, ln1b, l, hbuf);
    for (int pair = 0; pair < 2; pair++) {
      k_gemm_qkv<<<dim3(65, 12, 2), 256, 0, stream>>>(hbuf, wqkv_t, bqkv, pair, l, qbuf, kbuf, vbuf);
      k_attn<<<dim3(9, H_, 16), 256, 0, stream>>>(qbuf, kbuf, vbuf, pair, obuf);
    }
    k_gemm_res<<<dim3(65, 4, E_), 256, 0, stream>>>(obuf, wo_t, bo, l, tbuf);
    k_ln<<<dim3(S_, B_, E_), 256, 0, stream>>>(tbuf, ln2g, ln2b, l, hbuf);
    k_gemm_gelu<<<dim3(65, 4, E_), 256, 0, stream>>>(hbuf, w1_t, b1, l, obuf);
    k_gemm_res<<<dim3(65, 4, E_), 256, 0, stream>>>(obuf, w2_t, b2, l, tbuf);
  }
  k_lnf<<<32, 256, 0, stream>>>(tbuf, lnfg, lnfb, late);
  k_head<<<8, 256, 0, stream>>>(late, Wh, bh, gws, out);
}

// Round 8
// 1482.130 us; speedup vs baseline: 1.6163x; 1.0456x over previous
//
#include <hip/hip_runtime.h>
#include <hip/hip_bf16.h>
#include <math.h>

typedef __bf16 bf16_t;
typedef __bf16 bf16x4v __attribute__((ext_vector_type(4)));
typedef __bf16 bf16x8v __attribute__((ext_vector_type(8)));
typedef float  f32x4v  __attribute__((ext_vector_type(4)));

#define MFMA(a,b,c) __builtin_amdgcn_mfma_f32_16x16x32_bf16(a,b,c,0,0,0)

constexpr int B_ = 8, N_ = 1024, IN_ = 2048, DIM_ = 512, H_ = 8, DH_ = 64;
constexpr int DEPTH_ = 2, E_ = 4, C_ = 10, S_ = 1025;
constexpr int SP = 1152;        // padded seq len for q/k/v buffers (9*128)
constexpr int MP = 8320;        // padded row count for activations (65*128)
constexpr int MROWS = B_ * S_;  // 8200 valid rows per expert
constexpr size_t QKV_SLICE = (size_t)B_ * H_ * SP * DH_;  // one expert's q (or k/v)

// ---------------------------------------------------------------- async copy
__device__ __forceinline__ void async16(const void* g, void* l) {
  __builtin_amdgcn_global_load_lds((const __attribute__((address_space(1))) void*)g,
                                   (__attribute__((address_space(3))) void*)l, 16, 0, 0);
}

// ------------------------------------------------------- shared GEMM mainloop
// C[128x128] tile = A[128xK] * B^T[128xK]^T.  Both operands stored [rows][K]
// (weights pre-transposed). 4 waves in 2x2; each wave 64x64 via 4x4 MFMAs.
// LDS chunk-rotation swizzle: slot s of row R holds global 16B chunk
// (s - (R>>1)) & 3 -> conflict-free reads (R7: SQ_LDS_BANK_CONFLICT = 0).
__device__ __forceinline__ void gemm_core(const bf16_t* __restrict__ A,
                                          const bf16_t* __restrict__ Bm, int K,
                                          bf16_t* As, bf16_t* Bs,
                                          f32x4v acc[4][4]) {
  const int tid  = threadIdx.x;
  const int lane = tid & 63, wave = tid >> 6;
  const int fr = lane & 15, q4 = lane >> 4;
  const int wm = (wave >> 1) * 64, wn = (wave & 1) * 64;
  // staging: wave w fills rows [w*32, w*32+32) of both tiles
  const int srow = wave * 32 + (lane >> 2);
  const int scol = (((lane & 3) - (lane >> 3)) & 3) * 8;   // swizzled chunk
  const int sl   = ((q4 + (fr >> 1)) & 3) * 8;             // read-side slot
  const bf16_t* ga = A  + (size_t)srow * K + scol;
  const bf16_t* gb = Bm + (size_t)srow * K + scol;
  bf16_t* la = As + wave * 1024;  // wave-uniform LDS base; HW adds lane*16B
  bf16_t* lb = Bs + wave * 1024;
  for (int k0 = 0; k0 < K; k0 += 32) {
    async16(ga + k0,          la);
    async16(ga + k0 + 16 * K, la + 512);
    async16(gb + k0,          lb);
    async16(gb + k0 + 16 * K, lb + 512);
    __syncthreads();   // drains vmcnt(0): staged data visible
    bf16x8v af[4], bfr[4];
#pragma unroll
    for (int mt = 0; mt < 4; mt++)
      af[mt] = *(const bf16x8v*)&As[(wm + mt * 16 + fr) * 32 + sl];
#pragma unroll
    for (int nt = 0; nt < 4; nt++)
      bfr[nt] = *(const bf16x8v*)&Bs[(wn + nt * 16 + fr) * 32 + sl];
#pragma unroll
    for (int mt = 0; mt < 4; mt++)
#pragma unroll
      for (int nt = 0; nt < 4; nt++)
        acc[mt][nt] = MFMA(af[mt], bfr[nt], acc[mt][nt]);
    __syncthreads();   // all reads done before next stage overwrites
  }
}

// epilogue index helper: global row/col base for (mt,nt,r) iteration
#define EPI_SETUP()                                                    \
  int lane = threadIdx.x & 63, wave = threadIdx.x >> 6;                \
  int rb = blockIdx.x * 128 + (wave >> 1) * 64 + ((lane >> 4) << 2);   \
  int cb = blockIdx.y * 128 + (wave & 1) * 64 + (lane & 15);

// ----------------------------------------------------------------- converts
__global__ __launch_bounds__(256) void k_cvt(const float* __restrict__ in,
                                             bf16_t* __restrict__ out, int n4) {
  int i = blockIdx.x * blockDim.x + threadIdx.x;
  if (i < n4) {
    float4 v = ((const float4*)in)[i];
    bf16x4v o = {(bf16_t)v.x, (bf16_t)v.y, (bf16_t)v.z, (bf16_t)v.w};
    ((bf16x4v*)out)[i] = o;
  }
}

// in [nmat][K][N] f32 -> out [nmat][N][K] bf16 (K,N multiples of 32)
__global__ __launch_bounds__(256) void k_tcvt(const float* __restrict__ in,
                                              bf16_t* __restrict__ out, int K, int N) {
  __shared__ float tile[32][33];
  size_t mb = (size_t)blockIdx.z * K * N;
  int k0 = blockIdx.y * 32, n0 = blockIdx.x * 32;
  int tx = threadIdx.x, ty = threadIdx.y;
#pragma unroll
  for (int i = 0; i < 32; i += 8)
    tile[ty + i][tx] = in[mb + (size_t)(k0 + ty + i) * N + n0 + tx];
  __syncthreads();
#pragma unroll
  for (int i = 0; i < 32; i += 8)
    out[mb + (size_t)(n0 + ty + i) * K + k0 + tx] = (bf16_t)tile[tx][ty + i];
}

// ------------------------------------------------- proj GEMM (router+experts)
// z=0: router relu -> atomic mean-pool partials into racc[B][DIM]
// z=1..4: expert relu -> t[e][b][1+n][d]
__global__ __launch_bounds__(256) void k_gemm_proj(
    const bf16_t* __restrict__ xbf, const bf16_t* __restrict__ wrt,
    const bf16_t* __restrict__ wpt, const float* __restrict__ br,
    const float* __restrict__ bp, float* __restrict__ racc,
    float* __restrict__ t) {
  __shared__ bf16_t As[128 * 32], Bs[128 * 32];
  int z = blockIdx.z;
  const bf16_t* A  = xbf + (size_t)blockIdx.x * 128 * IN_;
  const bf16_t* Bm = (z == 0 ? wrt : wpt + (size_t)(z - 1) * DIM_ * IN_)
                     + (size_t)blockIdx.y * 128 * IN_;
  const float* bias = (z == 0) ? br : bp + (z - 1) * DIM_;
  f32x4v acc[4][4] = {};
  gemm_core(A, Bm, IN_, As, Bs, acc);
  EPI_SETUP();
  if (z == 0) {
    // all 128 rows of this block belong to batch b = blockIdx.x>>3
    int b = blockIdx.x >> 3;
    float part[4] = {0.f, 0.f, 0.f, 0.f};
#pragma unroll
    for (int mt = 0; mt < 4; mt++)
#pragma unroll
      for (int nt = 0; nt < 4; nt++)
#pragma unroll
        for (int r = 0; r < 4; r++)
          part[nt] += fmaxf(acc[mt][nt][r] + bias[cb + nt * 16], 0.f);
#pragma unroll
    for (int nt = 0; nt < 4; nt++)
      atomicAdd(&racc[b * DIM_ + cb + nt * 16], part[nt]);
  } else {
    int e = z - 1;
#pragma unroll
    for (int mt = 0; mt < 4; mt++)
#pragma unroll
      for (int nt = 0; nt < 4; nt++)
#pragma unroll
        for (int r = 0; r < 4; r++) {
          int row = rb + mt * 16 + r, col = cb + nt * 16;
          float v = fmaxf(acc[mt][nt][r] + bias[col], 0.f);
          int b = row >> 10, n = row & 1023;
          t[((size_t)(e * B_ + b) * S_ + 1 + n) * DIM_ + col] = v;
        }
  }
}

__global__ __launch_bounds__(512) void k_cls(const float* __restrict__ cls,
                                             float* __restrict__ t) {
  // block = (e*8+b); s=0 row
  t[(size_t)blockIdx.x * S_ * DIM_ + threadIdx.x] =
      cls[(blockIdx.x >> 3) * DIM_ + threadIdx.x];
}

// ------------------------------------------------------------------ router
__global__ __launch_bounds__(64) void k_router(const float* __restrict__ racc,
                                               const float* __restrict__ Wrf,
                                               const float* __restrict__ brf,
                                               float* __restrict__ gws,
                                               float* __restrict__ outg) {
  __shared__ float lg[8][4];
  int t = threadIdx.x;
  if (t < 32) {
    int b = t >> 2, e = t & 3;
    const float* r = racc + b * DIM_;
    float a = 0.f;
    for (int d = 0; d < DIM_; d++) a += r[d] * Wrf[d * 4 + e];
    lg[b][e] = a * (1.f / N_) + brf[e];
  }
  __syncthreads();
  if (t < 8) {
    int b = t;
    float mx = fmaxf(fmaxf(lg[b][0], lg[b][1]), fmaxf(lg[b][2], lg[b][3]));
    float s = 0.f, g[4];
#pragma unroll
    for (int e = 0; e < 4; e++) { g[e] = __expf(lg[b][e] - mx); s += g[e]; }
#pragma unroll
    for (int e = 0; e < 4; e++) {
      float gv = g[e] / s;
      gws[b * 4 + e] = gv;
      outg[b * 4 + e] = gv;
    }
  }
}

// ------------------------------- layernorm: one wave per row, 4 rows/block
// (R7's 1-row/256-thread version burned 33k blocks on cross-wave LDS
// reductions; wave-local xor-shuffle needs no LDS and no barrier.)
__global__ __launch_bounds__(256) void k_ln(const float* __restrict__ t,
                                            const float* __restrict__ gg,
                                            const float* __restrict__ bb, int l,
                                            bf16_t* __restrict__ h) {
  int r = blockIdx.x * 4 + (threadIdx.x >> 6);   // global row in [0, E*B*S)
  int lane = threadIdx.x & 63;
  int e = r / MROWS;
  const float* row = t + (size_t)r * DIM_;
  float v[8];
  float sum = 0.f, sq = 0.f;
#pragma unroll
  for (int i = 0; i < 8; i++) {
    v[i] = row[lane + 64 * i];
    sum += v[i]; sq += v[i] * v[i];
  }
#pragma unroll
  for (int o = 1; o < 64; o <<= 1) {
    sum += __shfl_xor(sum, o, 64);
    sq  += __shfl_xor(sq, o, 64);
  }
  float mean = sum * (1.f / DIM_);
  float var  = sq * (1.f / DIM_) - mean * mean;
  float rstd = rsqrtf(var + 1e-5f);
  const float* gp = gg + (size_t)(e * DEPTH_ + l) * DIM_;
  const float* bp = bb + (size_t)(e * DEPTH_ + l) * DIM_;
  bf16_t* orow = h + ((size_t)r + (size_t)e * (MP - MROWS)) * DIM_;
#pragma unroll
  for (int i = 0; i < 8; i++) {
    int d = lane + 64 * i;
    orow[d] = (bf16_t)((v[i] - mean) * rstd * gp[d] + bp[d]);
  }
}

__global__ __launch_bounds__(256) void k_lnf(const float* __restrict__ t,
                                             const float* __restrict__ gg,
                                             const float* __restrict__ bb,
                                             float* __restrict__ lat) {
  int eb = blockIdx.x, e = eb >> 3;
  const float* row = t + (size_t)eb * S_ * DIM_;  // s=0 (cls)
  int tid = threadIdx.x;
  float v0 = row[tid], v1 = row[tid + 256];
  float sum = v0 + v1, sq = v0 * v0 + v1 * v1;
  for (int o = 32; o > 0; o >>= 1) {
    sum += __shfl_down(sum, o, 64);
    sq  += __shfl_down(sq, o, 64);
  }
  __shared__ float sb[8];
  int lane = tid & 63, wave = tid >> 6;
  if (lane == 0) { sb[wave * 2] = sum; sb[wave * 2 + 1] = sq; }
  __syncthreads();
  float ts = sb[0] + sb[2] + sb[4] + sb[6];
  float tq = sb[1] + sb[3] + sb[5] + sb[7];
  float mean = ts * (1.f / DIM_);
  float var  = tq * (1.f / DIM_) - mean * mean;
  float rstd = rsqrtf(var + 1e-5f);
  lat[(size_t)eb * DIM_ + tid]       = (v0 - mean) * rstd * gg[e * DIM_ + tid] + bb[e * DIM_ + tid];
  lat[(size_t)eb * DIM_ + tid + 256] = (v1 - mean) * rstd * gg[e * DIM_ + tid + 256] + bb[e * DIM_ + tid + 256];
}

// ------------------------------------- QKV GEMM (two experts: pair*2 + z)
__global__ __launch_bounds__(256) void k_gemm_qkv(
    const bf16_t* __restrict__ h, const bf16_t* __restrict__ wt,
    const float* __restrict__ bias, int pair, int l, bf16_t* __restrict__ qb,
    bf16_t* __restrict__ kb, bf16_t* __restrict__ vb) {
  __shared__ bf16_t As[128 * 32], Bs[128 * 32];
  int esub = blockIdx.z, e = pair * 2 + esub;
  size_t slice = (size_t)esub * QKV_SLICE;
  const bf16_t* A  = h + ((size_t)e * MP + blockIdx.x * 128) * DIM_;
  const bf16_t* Bm = wt + ((size_t)(e * DEPTH_ + l) * (3 * DIM_) + blockIdx.y * 128) * DIM_;
  const float* bp = bias + (size_t)(e * DEPTH_ + l) * (3 * DIM_);
  f32x4v acc[4][4] = {};
  gemm_core(A, Bm, DIM_, As, Bs, acc);
  EPI_SETUP();
#pragma unroll
  for (int mt = 0; mt < 4; mt++)
#pragma unroll
    for (int nt = 0; nt < 4; nt++)
#pragma unroll
      for (int r = 0; r < 4; r++) {
        int row = rb + mt * 16 + r;
        if (row < MROWS) {
          int col = cb + nt * 16;
          float v = acc[mt][nt][r] + bp[col];
          int b = row / S_, s = row - b * S_;
          int which = col >> 9, d = col & 511;
          int hh = d >> 6, dh = d & 63;
          size_t bh = (size_t)b * H_ + hh;
          bf16_t bv = (bf16_t)v;
          if (which == 0)      qb[slice + (bh * SP + s) * DH_ + dh] = bv;
          else if (which == 1) kb[slice + (bh * SP + s) * DH_ + dh] = bv;
          else                 vb[slice + bh * DH_ * SP + (size_t)dh * SP + s] = bv;  // V^T
        }
      }
}

// --------------------------------- flash attention (two experts per launch)
// block = (qt128, head, esub*8+b); 4 waves, each owns 32 q-rows.  K/V tiles
// staged via global_load_lds once per block, double-buffered, XOR-swizzled.
// S^T trick: QK^T computed with operands SWAPPED -- MFMA(kf, qf) -- giving
// the C-frag key=row/query=col with the SAME register fragments (A and B
// per-lane layouts coincide for our loads).  Each lane's 4 p-values are then
// contiguous KEYS in the A-layout P buffer, so P spills as 8 ds_write_b64
// instead of 32 ds_write_b16 (R7: attention is LDS-pipe-bound, ~94% of time
// off the MFMA pipe).  No max-subtraction (|s| <~ 2); rowsum via ones-MFMA.
__global__ __launch_bounds__(256, 3) void k_attn(const bf16_t* __restrict__ qb,
                                                 const bf16_t* __restrict__ kb,
                                                 const bf16_t* __restrict__ vb,
                                                 int pair, bf16_t* __restrict__ ob) {
  __shared__ bf16_t P[4][32 * 72];
  __shared__ bf16_t Ks[2][4096], Vs[2][4096];
  int qt = blockIdx.x, hh = blockIdx.y;
  int esub = blockIdx.z >> 3, b = blockIdx.z & 7;
  int e = pair * 2 + esub;
  size_t slice = (size_t)esub * QKV_SLICE;
  size_t bh = (size_t)b * H_ + hh;
  const bf16_t* Q = qb + slice + bh * SP * DH_;
  const bf16_t* K = kb + slice + bh * SP * DH_;
  const bf16_t* V = vb + slice + bh * DH_ * SP;
  int lane = threadIdx.x & 63, wave = threadIdx.x >> 6;
  int fr = lane & 15, q4 = lane >> 4;
  int sw = fr & 7;                  // per-lane read-side swizzle
  bf16_t* Pw = &P[wave][0];

  // stage one 64x64 K tile + V tile (rows = key idx / dh; 8 chunks of 8 elems
  // per row). lds chunk p <- global (row=p>>3, ch=(p&7)^(row&7)).
  auto stage = [&](int buf, int ks) {
#pragma unroll
    for (int c = 0; c < 2; c++) {
      int p = c * 256 + wave * 64 + lane;
      int row = p >> 3;
      int ch = (p & 7) ^ (row & 7);
      bf16_t* lk = &Ks[buf][(c * 256 + wave * 64) * 8];  // wave-uniform base
      bf16_t* lv = &Vs[buf][(c * 256 + wave * 64) * 8];
      async16(K + (size_t)(ks + row) * DH_ + ch * 8, lk);
      async16(V + (size_t)row * SP + ks + ch * 8, lv);
    }
  };

  bf16x8v qf[2][2];
#pragma unroll
  for (int mt = 0; mt < 2; mt++)
#pragma unroll
    for (int kk = 0; kk < 2; kk++)
      qf[mt][kk] = *(const bf16x8v*)&Q[(size_t)(qt * 128 + wave * 32 + mt * 16 + fr) * DH_
                                       + q4 * 8 + kk * 32];

  bf16x8v ones;
#pragma unroll
  for (int j = 0; j < 8; j++) ones[j] = (bf16_t)1.0f;

  f32x4v O[2][4] = {};
  f32x4v lacc[2] = {};

  const float cl2e = 0.125f * 1.4426950408889634f;  // DH^-0.5 * log2(e)

  stage(0, 0);
  for (int kt = 0; kt < 17; kt++) {
    int cur = kt & 1, ks = kt * 64;
    __syncthreads();                 // vmcnt drain: buf[cur] staged & visible
    if (kt < 16) stage(1 - cur, ks + 64);  // in flight across this compute
    const bf16_t* Kb = &Ks[cur][0];
    const bf16_t* Vb = &Vs[cur][0];
    f32x4v sc[2][4] = {};            // S^T frag: key = q4*4+c, query = fr
#pragma unroll
    for (int nt = 0; nt < 4; nt++) {
      int rbase = (nt * 16 + fr) * 8;
      bf16x8v kf0 = *(const bf16x8v*)&Kb[(rbase + ((q4 + 0) ^ sw)) * 8];
      bf16x8v kf1 = *(const bf16x8v*)&Kb[(rbase + ((q4 + 4) ^ sw)) * 8];
#pragma unroll
      for (int mt = 0; mt < 2; mt++) {
        sc[mt][nt] = MFMA(kf0, qf[mt][0], sc[mt][nt]);
        sc[mt][nt] = MFMA(kf1, qf[mt][1], sc[mt][nt]);
      }
    }
    // mask invalid keys (rows of S^T frag; only last tile) -> p = 0 there
    if (ks + 64 > S_) {
#pragma unroll
      for (int nt = 0; nt < 4; nt++)
#pragma unroll
        for (int c = 0; c < 4; c++)
          if (ks + nt * 16 + q4 * 4 + c >= S_) {
#pragma unroll
            for (int mt = 0; mt < 2; mt++) sc[mt][nt][c] = -1e30f;
          }
    }
    // p = exp2(s*c); pack 4 contiguous keys -> one b64 LDS write (A layout)
#pragma unroll
    for (int mt = 0; mt < 2; mt++)
#pragma unroll
      for (int nt = 0; nt < 4; nt++) {
        bf16x4v pk;
#pragma unroll
        for (int c = 0; c < 4; c++)
          pk[c] = (bf16_t)exp2f(sc[mt][nt][c] * cl2e);
        *(bf16x4v*)&Pw[(mt * 16 + fr) * 72 + nt * 16 + q4 * 4] = pk;
      }
    // P @ V and P @ ones (rowsum) -- same-wave LDS write->read is in-order
#pragma unroll
    for (int kk = 0; kk < 2; kk++) {
      bf16x8v pa[2];
#pragma unroll
      for (int mt = 0; mt < 2; mt++) {
        pa[mt] = *(const bf16x8v*)&Pw[(mt * 16 + fr) * 72 + q4 * 8 + kk * 32];
        lacc[mt] = MFMA(pa[mt], ones, lacc[mt]);
      }
#pragma unroll
      for (int nt = 0; nt < 4; nt++) {
        bf16x8v vf = *(const bf16x8v*)&Vb[((nt * 16 + fr) * 8 + ((q4 + kk * 4) ^ sw)) * 8];
#pragma unroll
        for (int mt = 0; mt < 2; mt++)
          O[mt][nt] = MFMA(pa[mt], vf, O[mt][nt]);
      }
    }
  }
#pragma unroll
  for (int mt = 0; mt < 2; mt++)
#pragma unroll
    for (int c = 0; c < 4; c++) {
      int s = qt * 128 + wave * 32 + mt * 16 + q4 * 4 + c;
      if (s < S_) {
        float inv = 1.f / lacc[mt][c];
#pragma unroll
        for (int nt = 0; nt < 4; nt++)
          ob[((size_t)e * MP + (size_t)b * S_ + s) * DIM_ + hh * DH_ + nt * 16 + fr]
              = (bf16_t)(O[mt][nt][c] * inv);
      }
    }
}

// ------------------------------------------- GEMM + residual-add (Wo and W2)
__global__ __launch_bounds__(256) void k_gemm_res(
    const bf16_t* __restrict__ abuf, const bf16_t* __restrict__ wt,
    const float* __restrict__ bias, int l, float* __restrict__ t) {
  __shared__ bf16_t As[128 * 32], Bs[128 * 32];
  int e = blockIdx.z;
  const bf16_t* A  = abuf + ((size_t)e * MP + blockIdx.x * 128) * DIM_;
  const bf16_t* Bm = wt + ((size_t)(e * DEPTH_ + l) * DIM_ + blockIdx.y * 128) * DIM_;
  const float* bp = bias + (size_t)(e * DEPTH_ + l) * DIM_;
  f32x4v acc[4][4] = {};
  gemm_core(A, Bm, DIM_, As, Bs, acc);
  EPI_SETUP();
#pragma unroll
  for (int mt = 0; mt < 4; mt++)
#pragma unroll
    for (int nt = 0; nt < 4; nt++)
#pragma unroll
      for (int r = 0; r < 4; r++) {
        int row = rb + mt * 16 + r;
        if (row < MROWS) {
          int col = cb + nt * 16;
          t[((size_t)e * MROWS + row) * DIM_ + col] += acc[mt][nt][r] + bp[col];
        }
      }
}

// ----------------------------------------------------------- W1 GEMM + gelu
__global__ __launch_bounds__(256) void k_gemm_gelu(
    const bf16_t* __restrict__ abuf, const bf16_t* __restrict__ wt,
    const float* __restrict__ bias, int l, bf16_t* __restrict__ ub) {
  __shared__ bf16_t As[128 * 32], Bs[128 * 32];
  int e = blockIdx.z;
  const bf16_t* A  = abuf + ((size_t)e * MP + blockIdx.x * 128) * DIM_;
  const bf16_t* Bm = wt + ((size_t)(e * DEPTH_ + l) * DIM_ + blockIdx.y * 128) * DIM_;
  const float* bp = bias + (size_t)(e * DEPTH_ + l) * DIM_;
  f32x4v acc[4][4] = {};
  gemm_core(A, Bm, DIM_, As, Bs, acc);
  EPI_SETUP();
#pragma unroll
  for (int mt = 0; mt < 4; mt++)
#pragma unroll
    for (int nt = 0; nt < 4; nt++)
#pragma unroll
      for (int r = 0; r < 4; r++) {
        int row = rb + mt * 16 + r;
        if (row < MROWS) {
          int col = cb + nt * 16;
          float v = acc[mt][nt][r] + bp[col];
          // jax.nn.gelu tanh form; tanh(u) = 1 - 2/(exp(2u)+1) via fast exp
          float u2 = __expf(1.5957691216057308f * (v + 0.044715f * v * v * v));
          float th = 1.f - 2.f / (u2 + 1.f);
          float g = 0.5f * v * (1.f + th);
          ub[((size_t)e * MP + row) * DIM_ + col] = (bf16_t)g;
        }
      }
}

// ---------------------------------------------------------- head + mixtures
__global__ __launch_bounds__(256) void k_head(const float* __restrict__ lat,
                                              const float* __restrict__ Wh,
                                              const float* __restrict__ bh,
                                              const float* __restrict__ gws,
                                              float* __restrict__ out) {
  int b = blockIdx.x, tid = threadIdx.x;
  for (int d = tid; d < DIM_; d += 256) {
    float a = 0.f;
#pragma unroll
    for (int e = 0; e < 4; e++)
      a += gws[b * 4 + e] * lat[(size_t)(e * B_ + b) * DIM_ + d];
    out[b * DIM_ + d] = a;
  }
  __shared__ float lg[4][10];
  if (tid < 40) {
    int e = tid / 10, c = tid % 10;
    const float* le = lat + (size_t)(e * B_ + b) * DIM_;
    const float* w  = Wh + (size_t)e * DIM_ * C_;
    float a = 0.f;
    for (int d = 0; d < DIM_; d++) a += le[d] * w[d * C_ + c];
    lg[e][c] = a + bh[e * C_ + c];
  }
  __syncthreads();
  if (tid < 10) {
    float a = 0.f;
#pragma unroll
    for (int e = 0; e < 4; e++) a += gws[b * 4 + e] * lg[e][tid];
    out[B_ * DIM_ + b * C_ + tid] = a;
  }
}

// ------------------------------------------------------------------- launch
extern "C" void kernel_launch(void* const* d_in, const int* in_sizes, int n_in,
                              void* d_out, int out_size, void* d_ws, size_t ws_size,
                              hipStream_t stream) {
  const float* x    = (const float*)d_in[0];
  const float* Wr   = (const float*)d_in[1];
  const float* br   = (const float*)d_in[2];
  const float* Wrf  = (const float*)d_in[3];
  const float* brf  = (const float*)d_in[4];
  const float* Wp   = (const float*)d_in[5];
  const float* bp   = (const float*)d_in[6];
  const float* cls  = (const float*)d_in[7];
  const float* ln1g = (const float*)d_in[8];
  const float* ln1b = (const float*)d_in[9];
  const float* Wqkv = (const float*)d_in[10];
  const float* bqkv = (const float*)d_in[11];
  const float* Wo   = (const float*)d_in[12];
  const float* bo   = (const float*)d_in[13];
  const float* ln2g = (const float*)d_in[14];
  const float* ln2b = (const float*)d_in[15];
  const float* W1   = (const float*)d_in[16];
  const float* b1   = (const float*)d_in[17];
  const float* W2   = (const float*)d_in[18];
  const float* b2   = (const float*)d_in[19];
  const float* lnfg = (const float*)d_in[20];
  const float* lnfb = (const float*)d_in[21];
  const float* Wh   = (const float*)d_in[22];
  const float* bh   = (const float*)d_in[23];
  float* out = (float*)d_out;

  // ---- workspace layout (~210 MiB total; stream-ordered aliasing) ----
  char* w = (char*)d_ws;
  size_t off = 0;
  auto take = [&](size_t bytes) {
    void* p = w + off;
    off += (bytes + 255) & ~(size_t)255;
    return p;
  };
  // persistent region (~161 MiB)
  bf16_t* wqkv_t = (bf16_t*)take((size_t)E_ * DEPTH_ * 3 * DIM_ * DIM_ * 2);
  bf16_t* wo_t   = (bf16_t*)take((size_t)E_ * DEPTH_ * DIM_ * DIM_ * 2);
  bf16_t* w1_t   = (bf16_t*)take((size_t)E_ * DEPTH_ * DIM_ * DIM_ * 2);
  bf16_t* w2_t   = (bf16_t*)take((size_t)E_ * DEPTH_ * DIM_ * DIM_ * 2);
  float*  tbuf   = (float*)take((size_t)E_ * MROWS * DIM_ * 4);
  bf16_t* hbuf   = (bf16_t*)take((size_t)E_ * MP * DIM_ * 2);
  bf16_t* obuf   = (bf16_t*)take((size_t)E_ * MP * DIM_ * 2);  // attn out / W1 out
  float*  racc   = (float*)take((size_t)B_ * DIM_ * 4);
  float*  gws    = (float*)take((size_t)B_ * E_ * 4);
  float*  late   = (float*)take((size_t)E_ * B_ * DIM_ * 4);
  // union region (max of pre-loop view A=44 MiB, loop view B=57 MiB)
  char* uni = (char*)w + off;
  //   view A (dead after k_gemm_proj):
  bf16_t* x_bf = (bf16_t*)(uni);
  bf16_t* wr_t = (bf16_t*)(uni + (size_t)8192 * IN_ * 2);
  bf16_t* wp_t = (bf16_t*)(uni + (size_t)8192 * IN_ * 2 + (size_t)DIM_ * IN_ * 2);
  //   view B (2-expert q/k/v, rewritten every (l,pair)):
  size_t qkv2 = 2 * QKV_SLICE * 2;  // two experts, bytes
  bf16_t* qbuf = (bf16_t*)(uni);
  bf16_t* kbuf = (bf16_t*)(uni + qkv2);
  bf16_t* vbuf = (bf16_t*)(uni + 2 * qkv2);
  (void)in_sizes; (void)n_in; (void)out_size; (void)ws_size;

  // input + weight conversion (weights transposed to [N][K] bf16)
  int n4 = 8192 * IN_ / 4;
  k_cvt<<<(n4 + 255) / 256, 256, 0, stream>>>(x, x_bf, n4);
  dim3 tb(32, 8);
  k_tcvt<<<dim3(DIM_ / 32, IN_ / 32, 1), tb, 0, stream>>>(Wr, wr_t, IN_, DIM_);
  k_tcvt<<<dim3(DIM_ / 32, IN_ / 32, E_), tb, 0, stream>>>(Wp, wp_t, IN_, DIM_);
  k_tcvt<<<dim3(3 * DIM_ / 32, DIM_ / 32, E_ * DEPTH_), tb, 0, stream>>>(Wqkv, wqkv_t, DIM_, 3 * DIM_);
  k_tcvt<<<dim3(DIM_ / 32, DIM_ / 32, E_ * DEPTH_), tb, 0, stream>>>(Wo, wo_t, DIM_, DIM_);
  k_tcvt<<<dim3(DIM_ / 32, DIM_ / 32, E_ * DEPTH_), tb, 0, stream>>>(W1, w1_t, DIM_, DIM_);
  k_tcvt<<<dim3(DIM_ / 32, DIM_ / 32, E_ * DEPTH_), tb, 0, stream>>>(W2, w2_t, DIM_, DIM_);

  // router + expert input projections (z=0 router-pool, z=1..4 experts)
  hipMemsetAsync(racc, 0, (size_t)B_ * DIM_ * 4, stream);
  k_gemm_proj<<<dim3(64, 4, 5), 256, 0, stream>>>(x_bf, wr_t, wp_t, br, bp, racc, tbuf);
  k_cls<<<32, 512, 0, stream>>>(cls, tbuf);
  k_router<<<1, 64, 0, stream>>>(racc, Wrf, brf, gws, out + B_ * DIM_ + B_ * C_);

  for (int l = 0; l < DEPTH_; l++) {
    k_ln<<<MROWS * E_ / 4, 256, 0, stream>>>(tbuf, ln1g, ln1b, l, hbuf);
    for (int pair = 0; pair < 2; pair++) {
      k_gemm_qkv<<<dim3(65, 12, 2), 256, 0, stream>>>(hbuf, wqkv_t, bqkv, pair, l, qbuf, kbuf, vbuf);
      k_attn<<<dim3(9, H_, 16), 256, 0, stream>>>(qbuf, kbuf, vbuf, pair, obuf);
    }
    k_gemm_res<<<dim3(65, 4, E_), 256, 0, stream>>>(obuf, wo_t, bo, l, tbuf);
    k_ln<<<MROWS * E_ / 4, 256, 0, stream>>>(tbuf, ln2g, ln2b, l, hbuf);
    k_gemm_gelu<<<dim3(65, 4, E_), 256, 0, stream>>>(hbuf, w1_t, b1, l, obuf);
    k_gemm_res<<<dim3(65, 4, E_), 256, 0, stream>>>(obuf, w2_t, b2, l, tbuf);
  }
  k_lnf<<<32, 256, 0, stream>>>(tbuf, lnfg, lnfb, late);
  k_head<<<8, 256, 0, stream>>>(late, Wh, bh, gws, out);
}

// Round 9
// 1414.060 us; speedup vs baseline: 1.6941x; 1.0481x over previous
//
#include <hip/hip_runtime.h>
#include <hip/hip_bf16.h>
#include <math.h>

typedef __bf16 bf16_t;
typedef __bf16 bf16x4v __attribute__((ext_vector_type(4)));
typedef __bf16 bf16x8v __attribute__((ext_vector_type(8)));
typedef float  f32x4v  __attribute__((ext_vector_type(4)));

#define MFMA(a,b,c) __builtin_amdgcn_mfma_f32_16x16x32_bf16(a,b,c,0,0,0)

constexpr int B_ = 8, N_ = 1024, IN_ = 2048, DIM_ = 512, H_ = 8, DH_ = 64;
constexpr int DEPTH_ = 2, E_ = 4, C_ = 10, S_ = 1025;
constexpr int SP = 1152;        // padded seq len for q/k/v buffers (9*128)
constexpr int MP = 8320;        // padded row count for activations (65*128)
constexpr int MROWS = B_ * S_;  // 8200 valid rows per expert
constexpr size_t QKV_SLICE = (size_t)B_ * H_ * SP * DH_;  // one expert's q (or k/v)

// ---------------------------------------------------------------- async copy
__device__ __forceinline__ void async16(const void* g, void* l) {
  __builtin_amdgcn_global_load_lds((const __attribute__((address_space(1))) void*)g,
                                   (__attribute__((address_space(3))) void*)l, 16, 0, 0);
}

// ------------------------------------------------------- shared GEMM mainloop
// C[128x128] tile = A[128xK] * B^T[128xK]^T.  Both operands stored [rows][K]
// (weights pre-transposed). 4 waves in 2x2; each wave 64x64 via 4x4 MFMAs.
// LDS chunk-rotation swizzle: slot s of row R holds global 16B chunk
// (s - (R>>1)) & 3 -> conflict-free reads (R7: SQ_LDS_BANK_CONFLICT = 0).
// C-frag: m (frag row) = A-operand row, n (frag col, lane&15) = Bm-op row.
__device__ __forceinline__ void gemm_core(const bf16_t* __restrict__ A,
                                          const bf16_t* __restrict__ Bm, int K,
                                          bf16_t* As, bf16_t* Bs,
                                          f32x4v acc[4][4]) {
  const int tid  = threadIdx.x;
  const int lane = tid & 63, wave = tid >> 6;
  const int fr = lane & 15, q4 = lane >> 4;
  const int wm = (wave >> 1) * 64, wn = (wave & 1) * 64;
  // staging: wave w fills rows [w*32, w*32+32) of both tiles
  const int srow = wave * 32 + (lane >> 2);
  const int scol = (((lane & 3) - (lane >> 3)) & 3) * 8;   // swizzled chunk
  const int sl   = ((q4 + (fr >> 1)) & 3) * 8;             // read-side slot
  const bf16_t* ga = A  + (size_t)srow * K + scol;
  const bf16_t* gb = Bm + (size_t)srow * K + scol;
  bf16_t* la = As + wave * 1024;  // wave-uniform LDS base; HW adds lane*16B
  bf16_t* lb = Bs + wave * 1024;
  for (int k0 = 0; k0 < K; k0 += 32) {
    async16(ga + k0,          la);
    async16(ga + k0 + 16 * K, la + 512);
    async16(gb + k0,          lb);
    async16(gb + k0 + 16 * K, lb + 512);
    __syncthreads();   // drains vmcnt(0): staged data visible
    bf16x8v af[4], bfr[4];
#pragma unroll
    for (int mt = 0; mt < 4; mt++)
      af[mt] = *(const bf16x8v*)&As[(wm + mt * 16 + fr) * 32 + sl];
#pragma unroll
    for (int nt = 0; nt < 4; nt++)
      bfr[nt] = *(const bf16x8v*)&Bs[(wn + nt * 16 + fr) * 32 + sl];
#pragma unroll
    for (int mt = 0; mt < 4; mt++)
#pragma unroll
      for (int nt = 0; nt < 4; nt++)
        acc[mt][nt] = MFMA(af[mt], bfr[nt], acc[mt][nt]);
    __syncthreads();   // all reads done before next stage overwrites
  }
}

// epilogue index helper: global row/col base for (mt,nt,r) iteration
#define EPI_SETUP()                                                    \
  int lane = threadIdx.x & 63, wave = threadIdx.x >> 6;                \
  int rb = blockIdx.x * 128 + (wave >> 1) * 64 + ((lane >> 4) << 2);   \
  int cb = blockIdx.y * 128 + (wave & 1) * 64 + (lane & 15);

// ----------------------------------------------------------------- converts
__global__ __launch_bounds__(256) void k_cvt(const float* __restrict__ in,
                                             bf16_t* __restrict__ out, int n4) {
  int i = blockIdx.x * blockDim.x + threadIdx.x;
  if (i < n4) {
    float4 v = ((const float4*)in)[i];
    bf16x4v o = {(bf16_t)v.x, (bf16_t)v.y, (bf16_t)v.z, (bf16_t)v.w};
    ((bf16x4v*)out)[i] = o;
  }
}

// in [nmat][K][N] f32 -> out [nmat][N][K] bf16 (K,N multiples of 32)
__global__ __launch_bounds__(256) void k_tcvt(const float* __restrict__ in,
                                              bf16_t* __restrict__ out, int K, int N) {
  __shared__ float tile[32][33];
  size_t mb = (size_t)blockIdx.z * K * N;
  int k0 = blockIdx.y * 32, n0 = blockIdx.x * 32;
  int tx = threadIdx.x, ty = threadIdx.y;
#pragma unroll
  for (int i = 0; i < 32; i += 8)
    tile[ty + i][tx] = in[mb + (size_t)(k0 + ty + i) * N + n0 + tx];
  __syncthreads();
#pragma unroll
  for (int i = 0; i < 32; i += 8)
    out[mb + (size_t)(n0 + ty + i) * K + k0 + tx] = (bf16_t)tile[tx][ty + i];
}

// ------------------------------------------------- proj GEMM (router+experts)
// z=0: router relu -> atomic mean-pool partials into racc[B][DIM]
// z=1..4: expert relu -> t[e][b][1+n][d]
__global__ __launch_bounds__(256) void k_gemm_proj(
    const bf16_t* __restrict__ xbf, const bf16_t* __restrict__ wrt,
    const bf16_t* __restrict__ wpt, const float* __restrict__ br,
    const float* __restrict__ bp, float* __restrict__ racc,
    float* __restrict__ t) {
  __shared__ bf16_t As[128 * 32], Bs[128 * 32];
  int z = blockIdx.z;
  const bf16_t* A  = xbf + (size_t)blockIdx.x * 128 * IN_;
  const bf16_t* Bm = (z == 0 ? wrt : wpt + (size_t)(z - 1) * DIM_ * IN_)
                     + (size_t)blockIdx.y * 128 * IN_;
  const float* bias = (z == 0) ? br : bp + (z - 1) * DIM_;
  f32x4v acc[4][4] = {};
  gemm_core(A, Bm, IN_, As, Bs, acc);
  EPI_SETUP();
  if (z == 0) {
    // all 128 rows of this block belong to batch b = blockIdx.x>>3
    int b = blockIdx.x >> 3;
    float part[4] = {0.f, 0.f, 0.f, 0.f};
#pragma unroll
    for (int mt = 0; mt < 4; mt++)
#pragma unroll
      for (int nt = 0; nt < 4; nt++)
#pragma unroll
        for (int r = 0; r < 4; r++)
          part[nt] += fmaxf(acc[mt][nt][r] + bias[cb + nt * 16], 0.f);
#pragma unroll
    for (int nt = 0; nt < 4; nt++)
      atomicAdd(&racc[b * DIM_ + cb + nt * 16], part[nt]);
  } else {
    int e = z - 1;
#pragma unroll
    for (int mt = 0; mt < 4; mt++)
#pragma unroll
      for (int nt = 0; nt < 4; nt++)
#pragma unroll
        for (int r = 0; r < 4; r++) {
          int row = rb + mt * 16 + r, col = cb + nt * 16;
          float v = fmaxf(acc[mt][nt][r] + bias[col], 0.f);
          int b = row >> 10, n = row & 1023;
          t[((size_t)(e * B_ + b) * S_ + 1 + n) * DIM_ + col] = v;
        }
  }
}

__global__ __launch_bounds__(512) void k_cls(const float* __restrict__ cls,
                                             float* __restrict__ t) {
  // block = (e*8+b); s=0 row
  t[(size_t)blockIdx.x * S_ * DIM_ + threadIdx.x] =
      cls[(blockIdx.x >> 3) * DIM_ + threadIdx.x];
}

// ------------------------------------------------------------------ router
__global__ __launch_bounds__(64) void k_router(const float* __restrict__ racc,
                                               const float* __restrict__ Wrf,
                                               const float* __restrict__ brf,
                                               float* __restrict__ gws,
                                               float* __restrict__ outg) {
  __shared__ float lg[8][4];
  int t = threadIdx.x;
  if (t < 32) {
    int b = t >> 2, e = t & 3;
    const float* r = racc + b * DIM_;
    float a = 0.f;
    for (int d = 0; d < DIM_; d++) a += r[d] * Wrf[d * 4 + e];
    lg[b][e] = a * (1.f / N_) + brf[e];
  }
  __syncthreads();
  if (t < 8) {
    int b = t;
    float mx = fmaxf(fmaxf(lg[b][0], lg[b][1]), fmaxf(lg[b][2], lg[b][3]));
    float s = 0.f, g[4];
#pragma unroll
    for (int e = 0; e < 4; e++) { g[e] = __expf(lg[b][e] - mx); s += g[e]; }
#pragma unroll
    for (int e = 0; e < 4; e++) {
      float gv = g[e] / s;
      gws[b * 4 + e] = gv;
      outg[b * 4 + e] = gv;
    }
  }
}

// ------------------------------- layernorm: one wave per row, 4 rows/block
__global__ __launch_bounds__(256) void k_ln(const float* __restrict__ t,
                                            const float* __restrict__ gg,
                                            const float* __restrict__ bb, int l,
                                            bf16_t* __restrict__ h) {
  int r = blockIdx.x * 4 + (threadIdx.x >> 6);   // global row in [0, E*B*S)
  int lane = threadIdx.x & 63;
  int e = r / MROWS;
  const float* row = t + (size_t)r * DIM_;
  float v[8];
  float sum = 0.f, sq = 0.f;
#pragma unroll
  for (int i = 0; i < 8; i++) {
    v[i] = row[lane + 64 * i];
    sum += v[i]; sq += v[i] * v[i];
  }
#pragma unroll
  for (int o = 1; o < 64; o <<= 1) {
    sum += __shfl_xor(sum, o, 64);
    sq  += __shfl_xor(sq, o, 64);
  }
  float mean = sum * (1.f / DIM_);
  float var  = sq * (1.f / DIM_) - mean * mean;
  float rstd = rsqrtf(var + 1e-5f);
  const float* gp = gg + (size_t)(e * DEPTH_ + l) * DIM_;
  const float* bp = bb + (size_t)(e * DEPTH_ + l) * DIM_;
  bf16_t* orow = h + ((size_t)r + (size_t)e * (MP - MROWS)) * DIM_;
#pragma unroll
  for (int i = 0; i < 8; i++) {
    int d = lane + 64 * i;
    orow[d] = (bf16_t)((v[i] - mean) * rstd * gp[d] + bp[d]);
  }
}

__global__ __launch_bounds__(256) void k_lnf(const float* __restrict__ t,
                                             const float* __restrict__ gg,
                                             const float* __restrict__ bb,
                                             float* __restrict__ lat) {
  int eb = blockIdx.x, e = eb >> 3;
  const float* row = t + (size_t)eb * S_ * DIM_;  // s=0 (cls)
  int tid = threadIdx.x;
  float v0 = row[tid], v1 = row[tid + 256];
  float sum = v0 + v1, sq = v0 * v0 + v1 * v1;
  for (int o = 32; o > 0; o >>= 1) {
    sum += __shfl_down(sum, o, 64);
    sq  += __shfl_down(sq, o, 64);
  }
  __shared__ float sb[8];
  int lane = tid & 63, wave = tid >> 6;
  if (lane == 0) { sb[wave * 2] = sum; sb[wave * 2 + 1] = sq; }
  __syncthreads();
  float ts = sb[0] + sb[2] + sb[4] + sb[6];
  float tq = sb[1] + sb[3] + sb[5] + sb[7];
  float mean = ts * (1.f / DIM_);
  float var  = tq * (1.f / DIM_) - mean * mean;
  float rstd = rsqrtf(var + 1e-5f);
  lat[(size_t)eb * DIM_ + tid]       = (v0 - mean) * rstd * gg[e * DIM_ + tid] + bb[e * DIM_ + tid];
  lat[(size_t)eb * DIM_ + tid + 256] = (v1 - mean) * rstd * gg[e * DIM_ + tid + 256] + bb[e * DIM_ + tid + 256];
}

// ---------------------- QK GEMM (two experts; weight cols 0..1023 = q,k)
__global__ __launch_bounds__(256) void k_gemm_qk(
    const bf16_t* __restrict__ h, const bf16_t* __restrict__ wt,
    const float* __restrict__ bias, int pair, int l, bf16_t* __restrict__ qb,
    bf16_t* __restrict__ kb) {
  __shared__ bf16_t As[128 * 32], Bs[128 * 32];
  int esub = blockIdx.z, e = pair * 2 + esub;
  size_t slice = (size_t)esub * QKV_SLICE;
  const bf16_t* A  = h + ((size_t)e * MP + blockIdx.x * 128) * DIM_;
  const bf16_t* Bm = wt + ((size_t)(e * DEPTH_ + l) * (3 * DIM_) + blockIdx.y * 128) * DIM_;
  const float* bp = bias + (size_t)(e * DEPTH_ + l) * (3 * DIM_);
  f32x4v acc[4][4] = {};
  gemm_core(A, Bm, DIM_, As, Bs, acc);
  EPI_SETUP();
#pragma unroll
  for (int mt = 0; mt < 4; mt++)
#pragma unroll
    for (int nt = 0; nt < 4; nt++)
#pragma unroll
      for (int r = 0; r < 4; r++) {
        int row = rb + mt * 16 + r;
        if (row < MROWS) {
          int col = cb + nt * 16;
          float v = acc[mt][nt][r] + bp[col];
          int b = row / S_, s = row - b * S_;
          int which = col >> 9, d = col & 511;
          int hh = d >> 6, dh = d & 63;
          size_t bh = (size_t)b * H_ + hh;
          bf16_t bv = (bf16_t)v;
          if (which == 0) qb[slice + (bh * SP + s) * DH_ + dh] = bv;
          else            kb[slice + (bh * SP + s) * DH_ + dh] = bv;
        }
      }
}

// ---------------------- V GEMM (two experts), operand-SWAPPED gemm core:
// A = weight rows (V channels), Bm = activation rows.  The C-frag then has
// m = V channel, n = token row, so lane fr indexes consecutive tokens and the
// V^T store (vb[dh][s]) is 16x contiguous bf16 per quarter instead of the
// R8 stride-2304B scatter (16 cache-line transactions per store instr).
__global__ __launch_bounds__(256) void k_gemm_v(
    const bf16_t* __restrict__ h, const bf16_t* __restrict__ wt,
    const float* __restrict__ bias, int pair, int l, bf16_t* __restrict__ vb) {
  __shared__ bf16_t As[128 * 32], Bs[128 * 32];
  int esub = blockIdx.z, e = pair * 2 + esub;
  size_t slice = (size_t)esub * QKV_SLICE;
  const bf16_t* A  = wt + ((size_t)(e * DEPTH_ + l) * (3 * DIM_) + 1024 + blockIdx.y * 128) * DIM_;
  const bf16_t* Bm = h + ((size_t)e * MP + blockIdx.x * 128) * DIM_;
  const float* bp = bias + (size_t)(e * DEPTH_ + l) * (3 * DIM_) + 1024;
  f32x4v acc[4][4] = {};
  gemm_core(A, Bm, DIM_, As, Bs, acc);
  // swapped roles: frag row -> V channel, frag col -> token row
  int lane = threadIdx.x & 63, wave = threadIdx.x >> 6;
  int wb = blockIdx.y * 128 + (wave >> 1) * 64 + ((lane >> 4) << 2);
  int sb = blockIdx.x * 128 + (wave & 1) * 64 + (lane & 15);
#pragma unroll
  for (int mt = 0; mt < 4; mt++)
#pragma unroll
    for (int nt = 0; nt < 4; nt++)
#pragma unroll
      for (int r = 0; r < 4; r++) {
        int srow = sb + nt * 16;
        if (srow < MROWS) {
          int wch = wb + mt * 16 + r;        // 0..511 within V region
          float v = acc[mt][nt][r] + bp[wch];
          int b = srow / S_, s = srow - b * S_;
          int hh = wch >> 6, dh = wch & 63;
          vb[slice + ((size_t)b * H_ + hh) * DH_ * SP + (size_t)dh * SP + s] = (bf16_t)v;
        }
      }
}

// --------------------------------- flash attention (two experts per launch)
// block = (qt128, head, esub*8+b); 4 waves, each owns 32 q-rows.  K/V tiles
// staged via global_load_lds once per block, double-buffered, XOR-swizzled.
// S^T trick: QK^T computed with operands SWAPPED -- MFMA(kf, qf) -- so each
// lane's 4 p-values are contiguous KEYS: P spills as 8 ds_write_b64 instead
// of 32 ds_write_b16.  No max-subtraction (|s| <~ 2); rowsum via ones-MFMA.
__global__ __launch_bounds__(256, 3) void k_attn(const bf16_t* __restrict__ qb,
                                                 const bf16_t* __restrict__ kb,
                                                 const bf16_t* __restrict__ vb,
                                                 int pair, bf16_t* __restrict__ ob) {
  __shared__ bf16_t P[4][32 * 72];
  __shared__ bf16_t Ks[2][4096], Vs[2][4096];
  int qt = blockIdx.x, hh = blockIdx.y;
  int esub = blockIdx.z >> 3, b = blockIdx.z & 7;
  int e = pair * 2 + esub;
  size_t slice = (size_t)esub * QKV_SLICE;
  size_t bh = (size_t)b * H_ + hh;
  const bf16_t* Q = qb + slice + bh * SP * DH_;
  const bf16_t* K = kb + slice + bh * SP * DH_;
  const bf16_t* V = vb + slice + bh * DH_ * SP;
  int lane = threadIdx.x & 63, wave = threadIdx.x >> 6;
  int fr = lane & 15, q4 = lane >> 4;
  int sw = fr & 7;                  // per-lane read-side swizzle
  bf16_t* Pw = &P[wave][0];

  auto stage = [&](int buf, int ks) {
#pragma unroll
    for (int c = 0; c < 2; c++) {
      int p = c * 256 + wave * 64 + lane;
      int row = p >> 3;
      int ch = (p & 7) ^ (row & 7);
      bf16_t* lk = &Ks[buf][(c * 256 + wave * 64) * 8];  // wave-uniform base
      bf16_t* lv = &Vs[buf][(c * 256 + wave * 64) * 8];
      async16(K + (size_t)(ks + row) * DH_ + ch * 8, lk);
      async16(V + (size_t)row * SP + ks + ch * 8, lv);
    }
  };

  bf16x8v qf[2][2];
#pragma unroll
  for (int mt = 0; mt < 2; mt++)
#pragma unroll
    for (int kk = 0; kk < 2; kk++)
      qf[mt][kk] = *(const bf16x8v*)&Q[(size_t)(qt * 128 + wave * 32 + mt * 16 + fr) * DH_
                                       + q4 * 8 + kk * 32];

  bf16x8v ones;
#pragma unroll
  for (int j = 0; j < 8; j++) ones[j] = (bf16_t)1.0f;

  f32x4v O[2][4] = {};
  f32x4v lacc[2] = {};

  const float cl2e = 0.125f * 1.4426950408889634f;  // DH^-0.5 * log2(e)

  stage(0, 0);
  for (int kt = 0; kt < 17; kt++) {
    int cur = kt & 1, ks = kt * 64;
    __syncthreads();                 // vmcnt drain: buf[cur] staged & visible
    if (kt < 16) stage(1 - cur, ks + 64);  // in flight across this compute
    const bf16_t* Kb = &Ks[cur][0];
    const bf16_t* Vb = &Vs[cur][0];
    f32x4v sc[2][4] = {};            // S^T frag: key = q4*4+c, query = fr
#pragma unroll
    for (int nt = 0; nt < 4; nt++) {
      int rbase = (nt * 16 + fr) * 8;
      bf16x8v kf0 = *(const bf16x8v*)&Kb[(rbase + ((q4 + 0) ^ sw)) * 8];
      bf16x8v kf1 = *(const bf16x8v*)&Kb[(rbase + ((q4 + 4) ^ sw)) * 8];
#pragma unroll
      for (int mt = 0; mt < 2; mt++) {
        sc[mt][nt] = MFMA(kf0, qf[mt][0], sc[mt][nt]);
        sc[mt][nt] = MFMA(kf1, qf[mt][1], sc[mt][nt]);
      }
    }
    // mask invalid keys (rows of S^T frag; only last tile) -> p = 0 there
    if (ks + 64 > S_) {
#pragma unroll
      for (int nt = 0; nt < 4; nt++)
#pragma unroll
        for (int c = 0; c < 4; c++)
          if (ks + nt * 16 + q4 * 4 + c >= S_) {
#pragma unroll
            for (int mt = 0; mt < 2; mt++) sc[mt][nt][c] = -1e30f;
          }
    }
    // p = exp2(s*c); pack 4 contiguous keys -> one b64 LDS write (A layout)
#pragma unroll
    for (int mt = 0; mt < 2; mt++)
#pragma unroll
      for (int nt = 0; nt < 4; nt++) {
        bf16x4v pk;
#pragma unroll
        for (int c = 0; c < 4; c++)
          pk[c] = (bf16_t)exp2f(sc[mt][nt][c] * cl2e);
        *(bf16x4v*)&Pw[(mt * 16 + fr) * 72 + nt * 16 + q4 * 4] = pk;
      }
    // P @ V and P @ ones (rowsum) -- same-wave LDS write->read is in-order
#pragma unroll
    for (int kk = 0; kk < 2; kk++) {
      bf16x8v pa[2];
#pragma unroll
      for (int mt = 0; mt < 2; mt++) {
        pa[mt] = *(const bf16x8v*)&Pw[(mt * 16 + fr) * 72 + q4 * 8 + kk * 32];
        lacc[mt] = MFMA(pa[mt], ones, lacc[mt]);
      }
#pragma unroll
      for (int nt = 0; nt < 4; nt++) {
        bf16x8v vf = *(const bf16x8v*)&Vb[((nt * 16 + fr) * 8 + ((q4 + kk * 4) ^ sw)) * 8];
#pragma unroll
        for (int mt = 0; mt < 2; mt++)
          O[mt][nt] = MFMA(pa[mt], vf, O[mt][nt]);
      }
    }
  }
#pragma unroll
  for (int mt = 0; mt < 2; mt++)
#pragma unroll
    for (int c = 0; c < 4; c++) {
      int s = qt * 128 + wave * 32 + mt * 16 + q4 * 4 + c;
      if (s < S_) {
        float inv = 1.f / lacc[mt][c];
#pragma unroll
        for (int nt = 0; nt < 4; nt++)
          ob[((size_t)e * MP + (size_t)b * S_ + s) * DIM_ + hh * DH_ + nt * 16 + fr]
              = (bf16_t)(O[mt][nt][c] * inv);
      }
    }
}

// ------------------------------------------- GEMM + residual-add (Wo and W2)
__global__ __launch_bounds__(256) void k_gemm_res(
    const bf16_t* __restrict__ abuf, const bf16_t* __restrict__ wt,
    const float* __restrict__ bias, int l, float* __restrict__ t) {
  __shared__ bf16_t As[128 * 32], Bs[128 * 32];
  int e = blockIdx.z;
  const bf16_t* A  = abuf + ((size_t)e * MP + blockIdx.x * 128) * DIM_;
  const bf16_t* Bm = wt + ((size_t)(e * DEPTH_ + l) * DIM_ + blockIdx.y * 128) * DIM_;
  const float* bp = bias + (size_t)(e * DEPTH_ + l) * DIM_;
  f32x4v acc[4][4] = {};
  gemm_core(A, Bm, DIM_, As, Bs, acc);
  EPI_SETUP();
#pragma unroll
  for (int mt = 0; mt < 4; mt++)
#pragma unroll
    for (int nt = 0; nt < 4; nt++)
#pragma unroll
      for (int r = 0; r < 4; r++) {
        int row = rb + mt * 16 + r;
        if (row < MROWS) {
          int col = cb + nt * 16;
          t[((size_t)e * MROWS + row) * DIM_ + col] += acc[mt][nt][r] + bp[col];
        }
      }
}

// ----------------------------------------------------------- W1 GEMM + gelu
__global__ __launch_bounds__(256) void k_gemm_gelu(
    const bf16_t* __restrict__ abuf, const bf16_t* __restrict__ wt,
    const float* __restrict__ bias, int l, bf16_t* __restrict__ ub) {
  __shared__ bf16_t As[128 * 32], Bs[128 * 32];
  int e = blockIdx.z;
  const bf16_t* A  = abuf + ((size_t)e * MP + blockIdx.x * 128) * DIM_;
  const bf16_t* Bm = wt + ((size_t)(e * DEPTH_ + l) * DIM_ + blockIdx.y * 128) * DIM_;
  const float* bp = bias + (size_t)(e * DEPTH_ + l) * DIM_;
  f32x4v acc[4][4] = {};
  gemm_core(A, Bm, DIM_, As, Bs, acc);
  EPI_SETUP();
#pragma unroll
  for (int mt = 0; mt < 4; mt++)
#pragma unroll
    for (int nt = 0; nt < 4; nt++)
#pragma unroll
      for (int r = 0; r < 4; r++) {
        int row = rb + mt * 16 + r;
        if (row < MROWS) {
          int col = cb + nt * 16;
          float v = acc[mt][nt][r] + bp[col];
          // jax.nn.gelu tanh form; tanh(u) = 1 - 2/(exp(2u)+1) via fast exp
          float u2 = __expf(1.5957691216057308f * (v + 0.044715f * v * v * v));
          float th = 1.f - 2.f / (u2 + 1.f);
          float g = 0.5f * v * (1.f + th);
          ub[((size_t)e * MP + row) * DIM_ + col] = (bf16_t)g;
        }
      }
}

// ---------------------------------------------------------- head + mixtures
__global__ __launch_bounds__(256) void k_head(const float* __restrict__ lat,
                                              const float* __restrict__ Wh,
                                              const float* __restrict__ bh,
                                              const float* __restrict__ gws,
                                              float* __restrict__ out) {
  int b = blockIdx.x, tid = threadIdx.x;
  for (int d = tid; d < DIM_; d += 256) {
    float a = 0.f;
#pragma unroll
    for (int e = 0; e < 4; e++)
      a += gws[b * 4 + e] * lat[(size_t)(e * B_ + b) * DIM_ + d];
    out[b * DIM_ + d] = a;
  }
  __shared__ float lg[4][10];
  if (tid < 40) {
    int e = tid / 10, c = tid % 10;
    const float* le = lat + (size_t)(e * B_ + b) * DIM_;
    const float* w  = Wh + (size_t)e * DIM_ * C_;
    float a = 0.f;
    for (int d = 0; d < DIM_; d++) a += le[d] * w[d * C_ + c];
    lg[e][c] = a + bh[e * C_ + c];
  }
  __syncthreads();
  if (tid < 10) {
    float a = 0.f;
#pragma unroll
    for (int e = 0; e < 4; e++) a += gws[b * 4 + e] * lg[e][tid];
    out[B_ * DIM_ + b * C_ + tid] = a;
  }
}

// ------------------------------------------------------------------- launch
extern "C" void kernel_launch(void* const* d_in, const int* in_sizes, int n_in,
                              void* d_out, int out_size, void* d_ws, size_t ws_size,
                              hipStream_t stream) {
  const float* x    = (const float*)d_in[0];
  const float* Wr   = (const float*)d_in[1];
  const float* br   = (const float*)d_in[2];
  const float* Wrf  = (const float*)d_in[3];
  const float* brf  = (const float*)d_in[4];
  const float* Wp   = (const float*)d_in[5];
  const float* bp   = (const float*)d_in[6];
  const float* cls  = (const float*)d_in[7];
  const float* ln1g = (const float*)d_in[8];
  const float* ln1b = (const float*)d_in[9];
  const float* Wqkv = (const float*)d_in[10];
  const float* bqkv = (const float*)d_in[11];
  const float* Wo   = (const float*)d_in[12];
  const float* bo   = (const float*)d_in[13];
  const float* ln2g = (const float*)d_in[14];
  const float* ln2b = (const float*)d_in[15];
  const float* W1   = (const float*)d_in[16];
  const float* b1   = (const float*)d_in[17];
  const float* W2   = (const float*)d_in[18];
  const float* b2   = (const float*)d_in[19];
  const float* lnfg = (const float*)d_in[20];
  const float* lnfb = (const float*)d_in[21];
  const float* Wh   = (const float*)d_in[22];
  const float* bh   = (const float*)d_in[23];
  float* out = (float*)d_out;

  // ---- workspace layout (~218 MiB total; stream-ordered aliasing) ----
  char* w = (char*)d_ws;
  size_t off = 0;
  auto take = [&](size_t bytes) {
    void* p = w + off;
    off += (bytes + 255) & ~(size_t)255;
    return p;
  };
  // persistent region (~161 MiB)
  bf16_t* wqkv_t = (bf16_t*)take((size_t)E_ * DEPTH_ * 3 * DIM_ * DIM_ * 2);
  bf16_t* wo_t   = (bf16_t*)take((size_t)E_ * DEPTH_ * DIM_ * DIM_ * 2);
  bf16_t* w1_t   = (bf16_t*)take((size_t)E_ * DEPTH_ * DIM_ * DIM_ * 2);
  bf16_t* w2_t   = (bf16_t*)take((size_t)E_ * DEPTH_ * DIM_ * DIM_ * 2);
  float*  tbuf   = (float*)take((size_t)E_ * MROWS * DIM_ * 4);
  bf16_t* hbuf   = (bf16_t*)take((size_t)E_ * MP * DIM_ * 2);
  bf16_t* obuf   = (bf16_t*)take((size_t)E_ * MP * DIM_ * 2);  // attn out / W1 out
  float*  racc   = (float*)take((size_t)B_ * DIM_ * 4);
  float*  gws    = (float*)take((size_t)B_ * E_ * 4);
  float*  late   = (float*)take((size_t)E_ * B_ * DIM_ * 4);
  // union region (max of pre-loop view A=44 MiB, loop view B=57 MiB)
  char* uni = (char*)w + off;
  //   view A (dead after k_gemm_proj):
  bf16_t* x_bf = (bf16_t*)(uni);
  bf16_t* wr_t = (bf16_t*)(uni + (size_t)8192 * IN_ * 2);
  bf16_t* wp_t = (bf16_t*)(uni + (size_t)8192 * IN_ * 2 + (size_t)DIM_ * IN_ * 2);
  //   view B (2-expert q/k/v, rewritten every (l,pair)):
  size_t qkv2 = 2 * QKV_SLICE * 2;  // two experts, bytes
  bf16_t* qbuf = (bf16_t*)(uni);
  bf16_t* kbuf = (bf16_t*)(uni + qkv2);
  bf16_t* vbuf = (bf16_t*)(uni + 2 * qkv2);
  (void)in_sizes; (void)n_in; (void)out_size; (void)ws_size;

  // input + weight conversion (weights transposed to [N][K] bf16)
  int n4 = 8192 * IN_ / 4;
  k_cvt<<<(n4 + 255) / 256, 256, 0, stream>>>(x, x_bf, n4);
  dim3 tb(32, 8);
  k_tcvt<<<dim3(DIM_ / 32, IN_ / 32, 1), tb, 0, stream>>>(Wr, wr_t, IN_, DIM_);
  k_tcvt<<<dim3(DIM_ / 32, IN_ / 32, E_), tb, 0, stream>>>(Wp, wp_t, IN_, DIM_);
  k_tcvt<<<dim3(3 * DIM_ / 32, DIM_ / 32, E_ * DEPTH_), tb, 0, stream>>>(Wqkv, wqkv_t, DIM_, 3 * DIM_);
  k_tcvt<<<dim3(DIM_ / 32, DIM_ / 32, E_ * DEPTH_), tb, 0, stream>>>(Wo, wo_t, DIM_, DIM_);
  k_tcvt<<<dim3(DIM_ / 32, DIM_ / 32, E_ * DEPTH_), tb, 0, stream>>>(W1, w1_t, DIM_, DIM_);
  k_tcvt<<<dim3(DIM_ / 32, DIM_ / 32, E_ * DEPTH_), tb, 0, stream>>>(W2, w2_t, DIM_, DIM_);

  // router + expert input projections (z=0 router-pool, z=1..4 experts)
  hipMemsetAsync(racc, 0, (size_t)B_ * DIM_ * 4, stream);
  k_gemm_proj<<<dim3(64, 4, 5), 256, 0, stream>>>(x_bf, wr_t, wp_t, br, bp, racc, tbuf);
  k_cls<<<32, 512, 0, stream>>>(cls, tbuf);
  k_router<<<1, 64, 0, stream>>>(racc, Wrf, brf, gws, out + B_ * DIM_ + B_ * C_);

  for (int l = 0; l < DEPTH_; l++) {
    k_ln<<<MROWS * E_ / 4, 256, 0, stream>>>(tbuf, ln1g, ln1b, l, hbuf);
    for (int pair = 0; pair < 2; pair++) {
      k_gemm_qk<<<dim3(65, 8, 2), 256, 0, stream>>>(hbuf, wqkv_t, bqkv, pair, l, qbuf, kbuf);
      k_gemm_v<<<dim3(65, 4, 2), 256, 0, stream>>>(hbuf, wqkv_t, bqkv, pair, l, vbuf);
      k_attn<<<dim3(9, H_, 16), 256, 0, stream>>>(qbuf, kbuf, vbuf, pair, obuf);
    }
    k_gemm_res<<<dim3(65, 4, E_), 256, 0, stream>>>(obuf, wo_t, bo, l, tbuf);
    k_ln<<<MROWS * E_ / 4, 256, 0, stream>>>(tbuf, ln2g, ln2b, l, hbuf);
    k_gemm_gelu<<<dim3(65, 4, E_), 256, 0, stream>>>(hbuf, w1_t, b1, l, obuf);
    k_gemm_res<<<dim3(65, 4, E_), 256, 0, stream>>>(obuf, w2_t, b2, l, tbuf);
  }
  k_lnf<<<32, 256, 0, stream>>>(tbuf, lnfg, lnfb, late);
  k_head<<<8, 256, 0, stream>>>(late, Wh, bh, gws, out);
}